// Round 1
// baseline (215.916 us; speedup 1.0000x reference)
//
#include <hip/hip_runtime.h>

#define B_ 16
#define FDIM_ 512
#define LMAX_ 200
#define KC_ 1024

// ---------------------------------------------------------------------------
// K1: per (b,f): pq[k]=prom@Wq_p.T+bq_p ; A[j]=sum_k pq[k]*Wq_e[k*512+f,j] ;
//     C=sum_k pq[k]*bq_e[k*512+f] ; P=sum_k pq[k]*Wsig[k]+bsig
// ---------------------------------------------------------------------------
__global__ __launch_bounds__(256) void k_prep(
    const float* __restrict__ prom, const float* __restrict__ Wq_p,
    const float* __restrict__ bq_p, const float* __restrict__ Wq_e,
    const float* __restrict__ bq_e, const float* __restrict__ Wsig,
    const float* __restrict__ bsig,
    float* __restrict__ Aout, float* __restrict__ Cout, float* __restrict__ Pout)
{
    int t = blockIdx.x * 256 + threadIdx.x;
    if (t >= B_ * FDIM_) return;
    int b = t >> 9, f = t & 511;

    float pv[32];
    #pragma unroll
    for (int j = 0; j < 32; ++j) pv[j] = prom[b * 32 + j];

    float pq[32];
    #pragma unroll 4
    for (int k = 0; k < 32; ++k) {
        const float* wr = Wq_p + (size_t)(f * 32 + k) * 32;
        float s = bq_p[f * 32 + k];
        #pragma unroll
        for (int j = 0; j < 32; ++j) s += pv[j] * wr[j];
        pq[k] = s;
    }

    float Aacc[33];
    #pragma unroll
    for (int j = 0; j < 33; ++j) Aacc[j] = 0.f;
    float c = 0.f, ps = bsig[0];
    #pragma unroll 4
    for (int k = 0; k < 32; ++k) {
        const float* we = Wq_e + (size_t)(k * FDIM_ + f) * 33;
        float qk = pq[k];
        #pragma unroll
        for (int j = 0; j < 33; ++j) Aacc[j] += qk * we[j];
        c  += qk * bq_e[k * FDIM_ + f];
        ps += qk * Wsig[k];
    }
    float* ao = Aout + (size_t)t * 33;
    #pragma unroll
    for (int j = 0; j < 33; ++j) ao[j] = Aacc[j];
    Cout[t] = c;
    Pout[t] = ps;
}

// ---------------------------------------------------------------------------
// K2: one wave per (b,f). QK[l] = src[b,l]·A + C, *mask; layernorm over l=1..199;
//     S[bf][0] = P (prom_qms), S[bf][1..199] = normalized.
// ---------------------------------------------------------------------------
__global__ __launch_bounds__(256) void k_qk_ln(
    const float* __restrict__ src, const float* __restrict__ mask,
    const float* __restrict__ A, const float* __restrict__ C,
    const float* __restrict__ P, float* __restrict__ S)
{
    int gt = blockIdx.x * 256 + threadIdx.x;
    int wid = gt >> 6;              // = b*512+f
    int lane = threadIdx.x & 63;
    int b = wid >> 9;

    float Areg[33];
    const float* Ap = A + (size_t)wid * 33;
    #pragma unroll
    for (int j = 0; j < 33; ++j) Areg[j] = Ap[j];
    float Cv = C[wid];

    float q[4];
    float s1 = 0.f, s2 = 0.f;
    #pragma unroll
    for (int t = 0; t < 4; ++t) {
        int l = lane + t * 64;
        float val = 0.f;
        if (l < LMAX_) {
            const float* sr = src + ((size_t)b * LMAX_ + l) * 33;
            float s = Cv;
            #pragma unroll
            for (int j = 0; j < 33; ++j) s += sr[j] * Areg[j];
            val = s * mask[b * LMAX_ + l];
        }
        q[t] = val;
        if (l >= 1 && l < LMAX_) { s1 += val; s2 += val * val; }
    }
    #pragma unroll
    for (int off = 32; off > 0; off >>= 1) {
        s1 += __shfl_down(s1, off, 64);
        s2 += __shfl_down(s2, off, 64);
    }
    s1 = __shfl(s1, 0, 64);
    s2 = __shfl(s2, 0, 64);
    float mu  = s1 * (1.f / 199.f);
    float var = s2 * (1.f / 199.f) - mu * mu;
    float inv = 1.0f / sqrtf(var + 1e-5f);

    float* Sp = S + (size_t)wid * LMAX_;
    #pragma unroll
    for (int t = 0; t < 4; ++t) {
        int l = lane + t * 64;
        if (l == 0)            Sp[0] = P[wid];
        else if (l < LMAX_)    Sp[l] = (q[t] - mu) * inv;
    }
}

// ---------------------------------------------------------------------------
// Shared tiled GEMM: C[row,col] = sum_l A[row,l]*B[col,l]  (A @ B^T)
// 64x64 tile / 256 threads, 4x4 acc each, float4 LDS reads, XOR swizzle
// (col' = col ^ ((row>>2 & 7)<<2)) -> B-side reads 2-way (free), A broadcast.
// EPI: 0 none, 1 +bias+relu, 2 +bias
// ---------------------------------------------------------------------------
template<int KD, int CK, int EPI>
__global__ __launch_bounds__(256) void gemm_abT(
    const float* __restrict__ Ab, long asb,
    const float* __restrict__ Bb, long bsb,
    const float* __restrict__ bias,
    float* __restrict__ Cb, long csb, int cld)
{
    constexpr int F4  = CK / 4;      // float4 per row-chunk
    constexpr int NCH = KD / CK;
    __shared__ __align__(16) float As[64][64];
    __shared__ __align__(16) float Bs[64][64];

    int tid = threadIdx.x;
    int tx = tid & 15, ty = tid >> 4;
    int bz = blockIdx.z;
    const float* Arow = Ab + (size_t)bz * asb + (size_t)blockIdx.x * 64 * KD;
    const float* Brow = Bb + (size_t)bz * bsb + (size_t)blockIdx.y * 64 * KD;

    float acc[4][4] = {};

    for (int ch = 0; ch < NCH; ++ch) {
        int l0g = ch * CK;
        #pragma unroll
        for (int it = 0; it < (128 * F4) / 256; ++it) {
            int idx = it * 256 + tid;
            int which = idx >= 64 * F4;           // wave-uniform (64*F4 % 64 == 0)
            int id2 = which ? idx - 64 * F4 : idx;
            int r  = id2 / F4;
            int c4 = (id2 - r * F4) * 4;
            const float* gp = (which ? Brow : Arow) + (size_t)r * KD + l0g + c4;
            float4 v = *(const float4*)gp;
            float* sp = (which ? &Bs[0][0] : &As[0][0]) + r * 64 + (c4 ^ (((r >> 2) & 7) << 2));
            *(float4*)sp = v;
        }
        __syncthreads();
        #pragma unroll
        for (int g = 0; g < F4; ++g) {
            int l0 = g * 4;
            float4 av[4], bv[4];
            #pragma unroll
            for (int i = 0; i < 4; ++i)
                av[i] = *(const float4*)&As[ty * 4 + i][l0 ^ ((ty & 7) << 2)];
            #pragma unroll
            for (int j = 0; j < 4; ++j)
                bv[j] = *(const float4*)&Bs[tx * 4 + j][l0 ^ ((tx & 7) << 2)];
            #pragma unroll
            for (int i = 0; i < 4; ++i)
                #pragma unroll
                for (int j = 0; j < 4; ++j) {
                    acc[i][j] += av[i].x * bv[j].x;
                    acc[i][j] += av[i].y * bv[j].y;
                    acc[i][j] += av[i].z * bv[j].z;
                    acc[i][j] += av[i].w * bv[j].w;
                }
        }
        __syncthreads();
    }

    int row0 = blockIdx.x * 64 + ty * 4;
    int col0 = blockIdx.y * 64 + tx * 4;
    float4 bv4 = make_float4(0.f, 0.f, 0.f, 0.f);
    if (EPI) bv4 = *(const float4*)&bias[col0];
    #pragma unroll
    for (int i = 0; i < 4; ++i) {
        float4 v;
        v.x = acc[i][0]; v.y = acc[i][1]; v.z = acc[i][2]; v.w = acc[i][3];
        if (EPI) { v.x += bv4.x; v.y += bv4.y; v.z += bv4.z; v.w += bv4.w; }
        if (EPI == 1) {
            v.x = fmaxf(v.x, 0.f); v.y = fmaxf(v.y, 0.f);
            v.z = fmaxf(v.z, 0.f); v.w = fmaxf(v.w, 0.f);
        }
        *(float4*)&Cb[(size_t)bz * csb + (size_t)(row0 + i) * cld + col0] = v;
    }
}

// ---------------------------------------------------------------------------
extern "C" void kernel_launch(void* const* d_in, const int* in_sizes, int n_in,
                              void* d_out, int out_size, void* d_ws, size_t ws_size,
                              hipStream_t stream)
{
    const float* src  = (const float*)d_in[0];
    const float* prom = (const float*)d_in[1];
    const float* atac = (const float*)d_in[2];
    const float* mask = (const float*)d_in[3];
    const float* Wq_p = (const float*)d_in[4];
    const float* bq_p = (const float*)d_in[5];
    const float* Wq_e = (const float*)d_in[6];
    const float* bq_e = (const float*)d_in[7];
    const float* Wsig = (const float*)d_in[8];
    const float* bsig = (const float*)d_in[9];
    const float* W1   = (const float*)d_in[10];
    const float* b1   = (const float*)d_in[11];
    const float* W2   = (const float*)d_in[12];
    const float* b2   = (const float*)d_in[13];

    float* ws   = (float*)d_ws;
    float* Abuf = ws;                    // 16*512*33  = 270336
    float* Cbuf = Abuf + 270336;         // 8192
    float* Pbuf = Cbuf + 8192;           // 8192
    float* Sbuf = Pbuf + 8192;           // 16*512*200 = 1638400
    float* Qbuf = Sbuf + 1638400;        // 16*1024*512 = 8388608
    float* Hbuf = Qbuf + 8388608;        // 16384*128  = 2097152
    float* outp = (float*)d_out;

    hipLaunchKernelGGL(k_prep, dim3(32), dim3(256), 0, stream,
                       prom, Wq_p, bq_p, Wq_e, bq_e, Wsig, bsig, Abuf, Cbuf, Pbuf);

    hipLaunchKernelGGL(k_qk_ln, dim3(2048), dim3(256), 0, stream,
                       src, mask, Abuf, Cbuf, Pbuf, Sbuf);

    // QKall[b,k,f] = sum_{l=0..199} atac[b,k,l] * S[b,f,l]
    hipLaunchKernelGGL((gemm_abT<200, 40, 0>), dim3(16, 8, 16), dim3(256), 0, stream,
                       atac, (long)KC_ * LMAX_,
                       Sbuf, (long)FDIM_ * LMAX_,
                       nullptr,
                       Qbuf, (long)KC_ * FDIM_, FDIM_);

    // h = relu(QKall @ W1^T + b1) : (16384,512)x(128,512)^T
    hipLaunchKernelGGL((gemm_abT<512, 64, 1>), dim3(256, 2, 1), dim3(256), 0, stream,
                       Qbuf, 0L, W1, 0L, b1, Hbuf, 0L, 128);

    // out = h @ W2^T + b2 : (16384,128)x(64,128)^T
    hipLaunchKernelGGL((gemm_abT<128, 64, 2>), dim3(256, 1, 1), dim3(256), 0, stream,
                       Hbuf, 0L, W2, 0L, b2, outp, 0L, 64);
}

// Round 2
// 148.363 us; speedup vs baseline: 1.4553x; 1.4553x over previous
//
#include <hip/hip_runtime.h>

#define B_ 16
#define FDIM_ 512
#define LMAX_ 200
#define KC_ 1024

// ---------------------------------------------------------------------------
// K1: one block per f (512 blocks). LDS-staged:
//   pq[b][k] = prom[b]·Wq_p[f*32+k] + bq_p[f*32+k]
//   A[b][j]  = sum_k pq[b][k]*Wq_e[k*512+f][j]
//   C[b]     = sum_k pq[b][k]*bq_e[k*512+f]
//   P[b]     = sum_k pq[b][k]*Wsig[k] + bsig
// ---------------------------------------------------------------------------
__global__ __launch_bounds__(256) void k_prep(
    const float* __restrict__ prom, const float* __restrict__ Wq_p,
    const float* __restrict__ bq_p, const float* __restrict__ Wq_e,
    const float* __restrict__ bq_e, const float* __restrict__ Wsig,
    const float* __restrict__ bsig,
    float* __restrict__ Aout, float* __restrict__ Cout, float* __restrict__ Pout)
{
    int f = blockIdx.x;
    int tid = threadIdx.x;

    __shared__ float Wp[32][33];      // Wq_p rows f*32+k (padded: stride-33 kills bank conflict)
    __shared__ float We[32][33];      // Wq_e rows k*512+f
    __shared__ float promS[16][32];   // broadcast reads only
    __shared__ float pqS[16][33];
    __shared__ float bqpS[32], bqeS[32], wsigS[32];

    // Wq_p chunk: rows f*32..f*32+31 are 1024 contiguous floats at f*1024
    for (int i = tid; i < 1024; i += 256) {
        Wp[i >> 5][i & 31] = Wq_p[(size_t)f * 1024 + i];
    }
    // prom: 512 contiguous floats
    if (tid < 128) ((float4*)&promS[0][0])[tid] = ((const float4*)prom)[tid];
    // Wq_e rows k*512+f (33 floats each, stride 512 rows)
    for (int i = tid; i < 32 * 33; i += 256) {
        int k = i / 33, j = i - k * 33;
        We[k][j] = Wq_e[((size_t)(k * 512 + f)) * 33 + j];
    }
    if (tid < 32) {
        bqpS[tid]  = bq_p[f * 32 + tid];
        bqeS[tid]  = bq_e[tid * 512 + f];
        wsigS[tid] = Wsig[tid];
    }
    __syncthreads();

    // pq[b][k]: 512 dots of length 32
    for (int i = tid; i < 512; i += 256) {
        int b = i >> 5, k = i & 31;
        float s = bqpS[k];
        #pragma unroll
        for (int j = 0; j < 32; ++j) s += promS[b][j] * Wp[k][j];
        pqS[b][k] = s;
    }
    __syncthreads();

    // A[b][j]: 528 dots of length 32
    for (int i = tid; i < 16 * 33; i += 256) {
        int b = i / 33, j = i - b * 33;
        float s = 0.f;
        #pragma unroll
        for (int k = 0; k < 32; ++k) s += pqS[b][k] * We[k][j];
        Aout[((size_t)(b * 512 + f)) * 33 + j] = s;
    }
    // C, P
    if (tid < 16) {
        int b = tid;
        float c = 0.f, p = bsig[0];
        #pragma unroll
        for (int k = 0; k < 32; ++k) {
            c += pqS[b][k] * bqeS[k];
            p += pqS[b][k] * wsigS[k];
        }
        Cout[b * 512 + f] = c;
        Pout[b * 512 + f] = p;
    }
}

// ---------------------------------------------------------------------------
// K2: one wave per (b,f). QK[l] = src[b,l]·A + C, *mask; layernorm over l=1..199;
//     S[bf][0] = P (prom_qms), S[bf][1..199] = normalized.
// ---------------------------------------------------------------------------
__global__ __launch_bounds__(256) void k_qk_ln(
    const float* __restrict__ src, const float* __restrict__ mask,
    const float* __restrict__ A, const float* __restrict__ C,
    const float* __restrict__ P, float* __restrict__ S)
{
    int gt = blockIdx.x * 256 + threadIdx.x;
    int wid = gt >> 6;              // = b*512+f
    int lane = threadIdx.x & 63;
    int b = wid >> 9;

    float Areg[33];
    const float* Ap = A + (size_t)wid * 33;
    #pragma unroll
    for (int j = 0; j < 33; ++j) Areg[j] = Ap[j];
    float Cv = C[wid];

    float q[4];
    float s1 = 0.f, s2 = 0.f;
    #pragma unroll
    for (int t = 0; t < 4; ++t) {
        int l = lane + t * 64;
        float val = 0.f;
        if (l < LMAX_) {
            const float* sr = src + ((size_t)b * LMAX_ + l) * 33;
            float s = Cv;
            #pragma unroll
            for (int j = 0; j < 33; ++j) s += sr[j] * Areg[j];
            val = s * mask[b * LMAX_ + l];
        }
        q[t] = val;
        if (l >= 1 && l < LMAX_) { s1 += val; s2 += val * val; }
    }
    #pragma unroll
    for (int off = 32; off > 0; off >>= 1) {
        s1 += __shfl_down(s1, off, 64);
        s2 += __shfl_down(s2, off, 64);
    }
    s1 = __shfl(s1, 0, 64);
    s2 = __shfl(s2, 0, 64);
    float mu  = s1 * (1.f / 199.f);
    float var = s2 * (1.f / 199.f) - mu * mu;
    float inv = 1.0f / sqrtf(var + 1e-5f);

    float* Sp = S + (size_t)wid * LMAX_;
    #pragma unroll
    for (int t = 0; t < 4; ++t) {
        int l = lane + t * 64;
        if (l == 0)            Sp[0] = P[wid];
        else if (l < LMAX_)    Sp[l] = (q[t] - mu) * inv;
    }
}

// ---------------------------------------------------------------------------
// Shared tiled GEMM: C[row,col] = sum_l A[row,l]*B[col,l]  (A @ B^T)
// 64x64 tile / 256 threads, 4x4 acc each, float4 LDS reads, XOR swizzle
// (col' = col ^ ((row>>2 & 7)<<2)) -> B-side reads 2-way (free), A broadcast.
// EPI: 0 none, 1 +bias+relu, 2 +bias
// ---------------------------------------------------------------------------
template<int KD, int CK, int EPI>
__global__ __launch_bounds__(256) void gemm_abT(
    const float* __restrict__ Ab, long asb,
    const float* __restrict__ Bb, long bsb,
    const float* __restrict__ bias,
    float* __restrict__ Cb, long csb, int cld)
{
    constexpr int F4  = CK / 4;      // float4 per row-chunk
    constexpr int NCH = KD / CK;
    __shared__ __align__(16) float As[64][64];
    __shared__ __align__(16) float Bs[64][64];

    int tid = threadIdx.x;
    int tx = tid & 15, ty = tid >> 4;
    int bz = blockIdx.z;
    const float* Arow = Ab + (size_t)bz * asb + (size_t)blockIdx.x * 64 * KD;
    const float* Brow = Bb + (size_t)bz * bsb + (size_t)blockIdx.y * 64 * KD;

    float acc[4][4] = {};

    for (int ch = 0; ch < NCH; ++ch) {
        int l0g = ch * CK;
        #pragma unroll
        for (int it = 0; it < (128 * F4) / 256; ++it) {
            int idx = it * 256 + tid;
            int which = idx >= 64 * F4;           // wave-uniform (64*F4 % 64 == 0)
            int id2 = which ? idx - 64 * F4 : idx;
            int r  = id2 / F4;
            int c4 = (id2 - r * F4) * 4;
            const float* gp = (which ? Brow : Arow) + (size_t)r * KD + l0g + c4;
            float4 v = *(const float4*)gp;
            float* sp = (which ? &Bs[0][0] : &As[0][0]) + r * 64 + (c4 ^ (((r >> 2) & 7) << 2));
            *(float4*)sp = v;
        }
        __syncthreads();
        #pragma unroll
        for (int g = 0; g < F4; ++g) {
            int l0 = g * 4;
            float4 av[4], bv[4];
            #pragma unroll
            for (int i = 0; i < 4; ++i)
                av[i] = *(const float4*)&As[ty * 4 + i][l0 ^ ((ty & 7) << 2)];
            #pragma unroll
            for (int j = 0; j < 4; ++j)
                bv[j] = *(const float4*)&Bs[tx * 4 + j][l0 ^ ((tx & 7) << 2)];
            #pragma unroll
            for (int i = 0; i < 4; ++i)
                #pragma unroll
                for (int j = 0; j < 4; ++j) {
                    acc[i][j] += av[i].x * bv[j].x;
                    acc[i][j] += av[i].y * bv[j].y;
                    acc[i][j] += av[i].z * bv[j].z;
                    acc[i][j] += av[i].w * bv[j].w;
                }
        }
        __syncthreads();
    }

    int row0 = blockIdx.x * 64 + ty * 4;
    int col0 = blockIdx.y * 64 + tx * 4;
    float4 bv4 = make_float4(0.f, 0.f, 0.f, 0.f);
    if (EPI) bv4 = *(const float4*)&bias[col0];
    #pragma unroll
    for (int i = 0; i < 4; ++i) {
        float4 v;
        v.x = acc[i][0]; v.y = acc[i][1]; v.z = acc[i][2]; v.w = acc[i][3];
        if (EPI) { v.x += bv4.x; v.y += bv4.y; v.z += bv4.z; v.w += bv4.w; }
        if (EPI == 1) {
            v.x = fmaxf(v.x, 0.f); v.y = fmaxf(v.y, 0.f);
            v.z = fmaxf(v.z, 0.f); v.w = fmaxf(v.w, 0.f);
        }
        *(float4*)&Cb[(size_t)bz * csb + (size_t)(row0 + i) * cld + col0] = v;
    }
}

// ---------------------------------------------------------------------------
extern "C" void kernel_launch(void* const* d_in, const int* in_sizes, int n_in,
                              void* d_out, int out_size, void* d_ws, size_t ws_size,
                              hipStream_t stream)
{
    const float* src  = (const float*)d_in[0];
    const float* prom = (const float*)d_in[1];
    const float* atac = (const float*)d_in[2];
    const float* mask = (const float*)d_in[3];
    const float* Wq_p = (const float*)d_in[4];
    const float* bq_p = (const float*)d_in[5];
    const float* Wq_e = (const float*)d_in[6];
    const float* bq_e = (const float*)d_in[7];
    const float* Wsig = (const float*)d_in[8];
    const float* bsig = (const float*)d_in[9];
    const float* W1   = (const float*)d_in[10];
    const float* b1   = (const float*)d_in[11];
    const float* W2   = (const float*)d_in[12];
    const float* b2   = (const float*)d_in[13];

    float* ws   = (float*)d_ws;
    float* Abuf = ws;                    // 16*512*33  = 270336
    float* Cbuf = Abuf + 270336;         // 8192
    float* Pbuf = Cbuf + 8192;           // 8192
    float* Sbuf = Pbuf + 8192;           // 16*512*200 = 1638400
    float* Qbuf = Sbuf + 1638400;        // 16*1024*512 = 8388608
    float* Hbuf = Qbuf + 8388608;        // 16384*128  = 2097152
    float* outp = (float*)d_out;

    hipLaunchKernelGGL(k_prep, dim3(512), dim3(256), 0, stream,
                       prom, Wq_p, bq_p, Wq_e, bq_e, Wsig, bsig, Abuf, Cbuf, Pbuf);

    hipLaunchKernelGGL(k_qk_ln, dim3(2048), dim3(256), 0, stream,
                       src, mask, Abuf, Cbuf, Pbuf, Sbuf);

    // QKall[b,k,f] = sum_{l=0..199} atac[b,k,l] * S[b,f,l]
    hipLaunchKernelGGL((gemm_abT<200, 40, 0>), dim3(16, 8, 16), dim3(256), 0, stream,
                       atac, (long)KC_ * LMAX_,
                       Sbuf, (long)FDIM_ * LMAX_,
                       nullptr,
                       Qbuf, (long)KC_ * FDIM_, FDIM_);

    // h = relu(QKall @ W1^T + b1) : (16384,512)x(128,512)^T
    hipLaunchKernelGGL((gemm_abT<512, 64, 1>), dim3(256, 2, 1), dim3(256), 0, stream,
                       Qbuf, 0L, W1, 0L, b1, Hbuf, 0L, 128);

    // out = h @ W2^T + b2 : (16384,128)x(64,128)^T
    hipLaunchKernelGGL((gemm_abT<128, 64, 2>), dim3(256, 1, 1), dim3(256), 0, stream,
                       Hbuf, 0L, W2, 0L, b2, outp, 0L, 64);
}

// Round 3
// 84.658 us; speedup vs baseline: 2.5505x; 1.7525x over previous
//
#include <hip/hip_runtime.h>

#define B_ 16
#define FDIM_ 512
#define LMAX_ 200
#define KC_ 1024
#define KPAD_ 224

typedef __attribute__((ext_vector_type(8)))  _Float16 f16x8;
typedef __attribute__((ext_vector_type(4)))  float    floatx4;
typedef __attribute__((ext_vector_type(4)))  unsigned int uintx4;

// ---------------------------------------------------------------------------
// K1: one block per f (512 blocks). LDS-staged small-matrix prep.
// ---------------------------------------------------------------------------
__global__ __launch_bounds__(256) void k_prep(
    const float* __restrict__ prom, const float* __restrict__ Wq_p,
    const float* __restrict__ bq_p, const float* __restrict__ Wq_e,
    const float* __restrict__ bq_e, const float* __restrict__ Wsig,
    const float* __restrict__ bsig,
    float* __restrict__ Aout, float* __restrict__ Cout, float* __restrict__ Pout)
{
    int f = blockIdx.x;
    int tid = threadIdx.x;

    __shared__ float Wp[32][33];
    __shared__ float We[32][33];
    __shared__ float promS[16][32];
    __shared__ float pqS[16][33];
    __shared__ float bqpS[32], bqeS[32], wsigS[32];

    for (int i = tid; i < 1024; i += 256)
        Wp[i >> 5][i & 31] = Wq_p[(size_t)f * 1024 + i];
    if (tid < 128) ((float4*)&promS[0][0])[tid] = ((const float4*)prom)[tid];
    for (int i = tid; i < 32 * 33; i += 256) {
        int k = i / 33, j = i - k * 33;
        We[k][j] = Wq_e[((size_t)(k * 512 + f)) * 33 + j];
    }
    if (tid < 32) {
        bqpS[tid]  = bq_p[f * 32 + tid];
        bqeS[tid]  = bq_e[tid * 512 + f];
        wsigS[tid] = Wsig[tid];
    }
    __syncthreads();

    for (int i = tid; i < 512; i += 256) {
        int b = i >> 5, k = i & 31;
        float s = bqpS[k];
        #pragma unroll
        for (int j = 0; j < 32; ++j) s += promS[b][j] * Wp[k][j];
        pqS[b][k] = s;
    }
    __syncthreads();

    for (int i = tid; i < 16 * 33; i += 256) {
        int b = i / 33, j = i - b * 33;
        float s = 0.f;
        #pragma unroll
        for (int k = 0; k < 32; ++k) s += pqS[b][k] * We[k][j];
        Aout[((size_t)(b * 512 + f)) * 33 + j] = s;
    }
    if (tid < 16) {
        int b = tid;
        float c = 0.f, p = bsig[0];
        #pragma unroll
        for (int k = 0; k < 32; ++k) {
            c += pqS[b][k] * bqeS[k];
            p += pqS[b][k] * wsigS[k];
        }
        Cout[b * 512 + f] = c;
        Pout[b * 512 + f] = p;
    }
}

// ---------------------------------------------------------------------------
// K2: one wave per (b,f). QK -> mask -> layernorm(l=1..199); writes f16 S
// padded to 224: S[0]=P, S[1..199]=normed, S[200..223]=0.
// ---------------------------------------------------------------------------
__global__ __launch_bounds__(256) void k_qk_ln(
    const float* __restrict__ src, const float* __restrict__ mask,
    const float* __restrict__ A, const float* __restrict__ C,
    const float* __restrict__ P, _Float16* __restrict__ SB)
{
    int gt = blockIdx.x * 256 + threadIdx.x;
    int wid = gt >> 6;              // = b*512+f
    int lane = threadIdx.x & 63;
    int b = wid >> 9;

    float Areg[33];
    const float* Ap = A + (size_t)wid * 33;
    #pragma unroll
    for (int j = 0; j < 33; ++j) Areg[j] = Ap[j];
    float Cv = C[wid];

    float q[4];
    float s1 = 0.f, s2 = 0.f;
    #pragma unroll
    for (int t = 0; t < 4; ++t) {
        int l = lane + t * 64;
        float val = 0.f;
        if (l < LMAX_) {
            const float* sr = src + ((size_t)b * LMAX_ + l) * 33;
            float s = Cv;
            #pragma unroll
            for (int j = 0; j < 33; ++j) s += sr[j] * Areg[j];
            val = s * mask[b * LMAX_ + l];
        }
        q[t] = val;
        if (l >= 1 && l < LMAX_) { s1 += val; s2 += val * val; }
    }
    #pragma unroll
    for (int off = 32; off > 0; off >>= 1) {
        s1 += __shfl_down(s1, off, 64);
        s2 += __shfl_down(s2, off, 64);
    }
    s1 = __shfl(s1, 0, 64);
    s2 = __shfl(s2, 0, 64);
    float mu  = s1 * (1.f / 199.f);
    float var = s2 * (1.f / 199.f) - mu * mu;
    float inv = 1.0f / sqrtf(var + 1e-5f);

    _Float16* Sp = SB + (size_t)wid * KPAD_;
    #pragma unroll
    for (int t = 0; t < 4; ++t) {
        int l = lane + t * 64;
        if (l < KPAD_) {
            float v = (l == 0) ? P[wid] : ((l < LMAX_) ? (q[t] - mu) * inv : 0.f);
            Sp[l] = (_Float16)v;
        }
    }
}

// ---------------------------------------------------------------------------
// K3: f32 -> f16 conversions: atac (pad 200->224), W1, W2.
// ---------------------------------------------------------------------------
__global__ __launch_bounds__(256) void k_cvt(
    const float* __restrict__ atac, const float* __restrict__ W1,
    const float* __restrict__ W2, _Float16* __restrict__ atacB,
    _Float16* __restrict__ W1B, _Float16* __restrict__ W2B)
{
    const int TOT_A = B_ * KC_ * (KPAD_ / 8);     // 458752
    const int TOT_1 = (128 * 512) / 8;            // 8192
    const int TOT_2 = (64 * 128) / 8;             // 1024
    int t = blockIdx.x * 256 + threadIdx.x;
    if (t < TOT_A) {
        int row = t / 28, g = t - row * 28;
        f16x8 o;
        if (g < 25) {                              // l = g*8 .. g*8+7 < 200
            const float* s = atac + (size_t)row * LMAX_ + g * 8;
            float4 v0 = *(const float4*)s;
            float4 v1 = *(const float4*)(s + 4);
            o[0] = (_Float16)v0.x; o[1] = (_Float16)v0.y;
            o[2] = (_Float16)v0.z; o[3] = (_Float16)v0.w;
            o[4] = (_Float16)v1.x; o[5] = (_Float16)v1.y;
            o[6] = (_Float16)v1.z; o[7] = (_Float16)v1.w;
        } else {
            #pragma unroll
            for (int j = 0; j < 8; ++j) o[j] = (_Float16)0.f;
        }
        *(f16x8*)(atacB + (size_t)row * KPAD_ + g * 8) = o;
    } else if (t < TOT_A + TOT_1) {
        int t2 = t - TOT_A;
        const float* s = W1 + t2 * 8;
        f16x8 o;
        #pragma unroll
        for (int j = 0; j < 8; ++j) o[j] = (_Float16)s[j];
        *(f16x8*)(W1B + t2 * 8) = o;
    } else if (t < TOT_A + TOT_1 + TOT_2) {
        int t2 = t - TOT_A - TOT_1;
        const float* s = W2 + t2 * 8;
        f16x8 o;
        #pragma unroll
        for (int j = 0; j < 8; ++j) o[j] = (_Float16)s[j];
        *(f16x8*)(W2B + t2 * 8) = o;
    }
}

// ---------------------------------------------------------------------------
// MFMA GEMM: C[row,col] = sum_k A[row,k]*B[col,k]  (A @ B^T), f16 in, f32 acc.
// Block: 256 thr / 4 waves, tile 128 x NT. NT=128: wave 64x64 (acc 4x4);
// NT=64: wave 32x64 (acc 2x4). BK=32, reg-staged LDS, linear layout
// (ds_read_b128 fragment pattern is bank-even; no swizzle needed).
// EPI: 0 none->f16, 1 bias+relu->f16, 2 bias->f32
// ---------------------------------------------------------------------------
template<int KD, int NT, int EPI>
__global__ __launch_bounds__(256) void gemm_mfma(
    const _Float16* __restrict__ Ab, long asb, int lda,
    const _Float16* __restrict__ Bb, long bsb, int ldb,
    const float* __restrict__ bias,
    void* __restrict__ Cb, long csb, int ldc)
{
    constexpr int NCH = KD / 32;
    constexpr int nWc = NT / 64;            // 2 or 1
    constexpr int WM  = (NT == 128) ? 64 : 32;
    constexpr int MR  = WM / 16;            // 4 or 2
    constexpr int BLB = (NT * 4) / 256;     // B-stage loads per thread (2 or 1)

    __shared__ unsigned short At[128 * 32];
    __shared__ unsigned short Bt[NT * 32];

    int tid  = threadIdx.x;
    int wid  = tid >> 6, lane = tid & 63;
    int wr   = wid / nWc, wc = wid % nWc;
    int l15  = lane & 15, l4 = lane >> 4;

    const _Float16* Abase = Ab + (size_t)blockIdx.z * asb + (size_t)blockIdx.x * 128 * lda;
    const _Float16* Bbase = Bb + (size_t)blockIdx.z * bsb + (size_t)blockIdx.y * NT  * ldb;

    floatx4 acc[MR][4];
    #pragma unroll
    for (int m = 0; m < MR; ++m)
        #pragma unroll
        for (int n = 0; n < 4; ++n)
            acc[m][n] = (floatx4){0.f, 0.f, 0.f, 0.f};

    for (int ch = 0; ch < NCH; ++ch) {
        int k0 = ch * 32;
        #pragma unroll
        for (int it = 0; it < 2; ++it) {           // A: 512 slots
            int i = it * 256 + tid;
            int r = i >> 2, s = i & 3;
            uintx4 v = *(const uintx4*)(Abase + (size_t)r * lda + k0 + s * 8);
            *(uintx4*)&At[i * 8] = v;
        }
        #pragma unroll
        for (int it = 0; it < BLB; ++it) {         // B: NT*4 slots
            int i = it * 256 + tid;
            int r = i >> 2, s = i & 3;
            uintx4 v = *(const uintx4*)(Bbase + (size_t)r * ldb + k0 + s * 8);
            *(uintx4*)&Bt[i * 8] = v;
        }
        __syncthreads();

        f16x8 av[MR], bv[4];
        #pragma unroll
        for (int m = 0; m < MR; ++m)
            av[m] = *(const f16x8*)&At[(wr * WM + m * 16 + l15) * 32 + l4 * 8];
        #pragma unroll
        for (int n = 0; n < 4; ++n)
            bv[n] = *(const f16x8*)&Bt[(wc * 64 + n * 16 + l15) * 32 + l4 * 8];
        #pragma unroll
        for (int m = 0; m < MR; ++m)
            #pragma unroll
            for (int n = 0; n < 4; ++n)
                acc[m][n] = __builtin_amdgcn_mfma_f32_16x16x32_f16(
                    av[m], bv[n], acc[m][n], 0, 0, 0);
        __syncthreads();
    }

    int rb = blockIdx.x * 128 + wr * WM;
    int cb = blockIdx.y * NT  + wc * 64;

    float bc[4];
    if (EPI) {
        #pragma unroll
        for (int n = 0; n < 4; ++n) bc[n] = bias[cb + n * 16 + l15];
    }

    #pragma unroll
    for (int m = 0; m < MR; ++m) {
        #pragma unroll
        for (int n = 0; n < 4; ++n) {
            #pragma unroll
            for (int q = 0; q < 4; ++q) {
                int row = rb + m * 16 + l4 * 4 + q;
                int col = cb + n * 16 + l15;
                float v = acc[m][n][q];
                if (EPI) v += bc[n];
                if (EPI == 1) v = fmaxf(v, 0.f);
                if (EPI == 2) {
                    ((float*)Cb)[(size_t)blockIdx.z * csb + (size_t)row * ldc + col] = v;
                } else {
                    ((_Float16*)Cb)[(size_t)blockIdx.z * csb + (size_t)row * ldc + col] = (_Float16)v;
                }
            }
        }
    }
}

// ---------------------------------------------------------------------------
extern "C" void kernel_launch(void* const* d_in, const int* in_sizes, int n_in,
                              void* d_out, int out_size, void* d_ws, size_t ws_size,
                              hipStream_t stream)
{
    const float* src  = (const float*)d_in[0];
    const float* prom = (const float*)d_in[1];
    const float* atac = (const float*)d_in[2];
    const float* mask = (const float*)d_in[3];
    const float* Wq_p = (const float*)d_in[4];
    const float* bq_p = (const float*)d_in[5];
    const float* Wq_e = (const float*)d_in[6];
    const float* bq_e = (const float*)d_in[7];
    const float* Wsig = (const float*)d_in[8];
    const float* bsig = (const float*)d_in[9];
    const float* W1   = (const float*)d_in[10];
    const float* b1   = (const float*)d_in[11];
    const float* W2   = (const float*)d_in[12];
    const float* b2   = (const float*)d_in[13];

    float* ws   = (float*)d_ws;
    float* Abuf = ws;                        // 16*512*33 = 270336 f32
    float* Cbuf = Abuf + 270336;             // 8192
    float* Pbuf = Cbuf + 8192;               // 8192
    _Float16* SB    = (_Float16*)(Pbuf + 8192);      // 16*512*224  = 1835008
    _Float16* atacB = SB + 1835008;                  // 16*1024*224 = 3670016
    _Float16* W1B   = atacB + 3670016;               // 65536
    _Float16* W2B   = W1B + 65536;                   // 8192
    _Float16* Qbuf  = W2B + 8192;                    // 16*1024*512 = 8388608
    _Float16* Hbuf  = Qbuf + 8388608;                // 16384*128   = 2097152
    float* outp = (float*)d_out;

    hipLaunchKernelGGL(k_prep, dim3(512), dim3(256), 0, stream,
                       prom, Wq_p, bq_p, Wq_e, bq_e, Wsig, bsig, Abuf, Cbuf, Pbuf);

    hipLaunchKernelGGL(k_qk_ln, dim3(2048), dim3(256), 0, stream,
                       src, mask, Abuf, Cbuf, Pbuf, SB);

    hipLaunchKernelGGL(k_cvt, dim3((458752 + 8192 + 1024 + 255) / 256), dim3(256), 0, stream,
                       atac, W1, W2, atacB, W1B, W2B);

    // QKall[b,k,f] = sum_l atacB[b,k,l] * SB[b,f,l]   (K padded to 224)
    hipLaunchKernelGGL((gemm_mfma<KPAD_, 128, 0>), dim3(8, 4, 16), dim3(256), 0, stream,
                       atacB, (long)KC_ * KPAD_, KPAD_,
                       SB,    (long)FDIM_ * KPAD_, KPAD_,
                       nullptr,
                       (void*)Qbuf, (long)KC_ * FDIM_, FDIM_);

    // h = relu(QKall @ W1^T + b1) : (16384,512) x (128,512)^T -> f16
    hipLaunchKernelGGL((gemm_mfma<512, 128, 1>), dim3(128, 1, 1), dim3(256), 0, stream,
                       Qbuf, 0L, 512,
                       W1B,  0L, 512,
                       b1,
                       (void*)Hbuf, 0L, 128);

    // out = h @ W2^T + b2 : (16384,128) x (64,128)^T -> f32
    hipLaunchKernelGGL((gemm_mfma<128, 64, 2>), dim3(128, 1, 1), dim3(256), 0, stream,
                       Hbuf, 0L, 128,
                       W2B,  0L, 128,
                       b2,
                       (void*)outp, 0L, 64);
}

// Round 4
// 72.128 us; speedup vs baseline: 2.9935x; 1.1737x over previous
//
#include <hip/hip_runtime.h>

#define B_ 16
#define FDIM_ 512
#define LMAX_ 200
#define KC_ 1024
#define KPAD_ 256

typedef __attribute__((ext_vector_type(8)))  _Float16 f16x8;
typedef __attribute__((ext_vector_type(4)))  float    floatx4;

// ---------------------------------------------------------------------------
// K1: one block per f (512 blocks). LDS-staged small-matrix prep.
//   pq[b][k] = prom[b]·Wq_p[f*32+k] + bq_p ; A[b][j] = sum_k pq*Wq_e ;
//   C[b] = sum_k pq*bq_e ; P[b] = sum_k pq*Wsig + bsig
// ---------------------------------------------------------------------------
__global__ __launch_bounds__(256) void k_prep(
    const float* __restrict__ prom, const float* __restrict__ Wq_p,
    const float* __restrict__ bq_p, const float* __restrict__ Wq_e,
    const float* __restrict__ bq_e, const float* __restrict__ Wsig,
    const float* __restrict__ bsig,
    float* __restrict__ Aout, float* __restrict__ Cout, float* __restrict__ Pout)
{
    int f = blockIdx.x;
    int tid = threadIdx.x;

    __shared__ float Wp[32][33];
    __shared__ float We[32][33];
    __shared__ float promS[16][32];
    __shared__ float pqS[16][33];
    __shared__ float bqpS[32], bqeS[32], wsigS[32];

    for (int i = tid; i < 1024; i += 256)
        Wp[i >> 5][i & 31] = Wq_p[(size_t)f * 1024 + i];
    if (tid < 128) ((float4*)&promS[0][0])[tid] = ((const float4*)prom)[tid];
    for (int i = tid; i < 32 * 33; i += 256) {
        int k = i / 33, j = i - k * 33;
        We[k][j] = Wq_e[((size_t)(k * 512 + f)) * 33 + j];
    }
    if (tid < 32) {
        bqpS[tid]  = bq_p[f * 32 + tid];
        bqeS[tid]  = bq_e[tid * 512 + f];
        wsigS[tid] = Wsig[tid];
    }
    __syncthreads();

    for (int i = tid; i < 512; i += 256) {
        int b = i >> 5, k = i & 31;
        float s = bqpS[k];
        #pragma unroll
        for (int j = 0; j < 32; ++j) s += promS[b][j] * Wp[k][j];
        pqS[b][k] = s;
    }
    __syncthreads();

    for (int i = tid; i < 16 * 33; i += 256) {
        int b = i / 33, j = i - b * 33;
        float s = 0.f;
        #pragma unroll
        for (int k = 0; k < 32; ++k) s += pqS[b][k] * We[k][j];
        Aout[((size_t)(b * 512 + f)) * 33 + j] = s;
    }
    if (tid < 16) {
        int b = tid;
        float c = 0.f, p = bsig[0];
        #pragma unroll
        for (int k = 0; k < 32; ++k) {
            c += pqS[b][k] * bqeS[k];
            p += pqS[b][k] * wsigS[k];
        }
        Cout[b * 512 + f] = c;
        Pout[b * 512 + f] = p;
    }
}

// ---------------------------------------------------------------------------
// K2: one wave per (b,f). QK -> mask -> layernorm(l=1..199); writes f16 S,
// stride 256: S[0]=P, S[1..199]=normed, S[200..255]=0.
// ---------------------------------------------------------------------------
__global__ __launch_bounds__(256) void k_qk_ln(
    const float* __restrict__ src, const float* __restrict__ mask,
    const float* __restrict__ A, const float* __restrict__ C,
    const float* __restrict__ P, _Float16* __restrict__ SB)
{
    int gt = blockIdx.x * 256 + threadIdx.x;
    int wid = gt >> 6;              // = b*512+f
    int lane = threadIdx.x & 63;
    int b = wid >> 9;

    float Areg[33];
    const float* Ap = A + (size_t)wid * 33;
    #pragma unroll
    for (int j = 0; j < 33; ++j) Areg[j] = Ap[j];
    float Cv = C[wid];

    float q[4];
    float s1 = 0.f, s2 = 0.f;
    #pragma unroll
    for (int t = 0; t < 4; ++t) {
        int l = lane + t * 64;
        float val = 0.f;
        if (l < LMAX_) {
            const float* sr = src + ((size_t)b * LMAX_ + l) * 33;
            float s = Cv;
            #pragma unroll
            for (int j = 0; j < 33; ++j) s += sr[j] * Areg[j];
            val = s * mask[b * LMAX_ + l];
        }
        q[t] = val;
        if (l >= 1 && l < LMAX_) { s1 += val; s2 += val * val; }
    }
    #pragma unroll
    for (int off = 32; off > 0; off >>= 1) {
        s1 += __shfl_down(s1, off, 64);
        s2 += __shfl_down(s2, off, 64);
    }
    s1 = __shfl(s1, 0, 64);
    s2 = __shfl(s2, 0, 64);
    float mu  = s1 * (1.f / 199.f);
    float var = s2 * (1.f / 199.f) - mu * mu;
    float inv = 1.0f / sqrtf(var + 1e-5f);

    _Float16* Sp = SB + (size_t)wid * KPAD_;
    #pragma unroll
    for (int t = 0; t < 4; ++t) {
        int l = lane + t * 64;   // covers 0..255 exactly
        float v = (l == 0) ? P[wid] : ((l < LMAX_) ? (q[t] - mu) * inv : 0.f);
        Sp[l] = (_Float16)v;
    }
}

// ---------------------------------------------------------------------------
// K3: QKall GEMM. C[kcell,f] = sum_l atac[b,kcell,l] * SB[b,f,l].
// Tile 128x128, 4 waves (2x2 of 64x64), BK=64, K=256 (l padded, zeros inert).
// atac converted f32->f16 during reg-staging. LDS XOR-swizzled (g ^= row&7).
// ---------------------------------------------------------------------------
__global__ __launch_bounds__(256) void k_gemm_qk(
    const float* __restrict__ atac, const _Float16* __restrict__ SB,
    _Float16* __restrict__ Q)
{
    __shared__ _Float16 At[128 * 64];
    __shared__ _Float16 Bt[128 * 64];

    int tid = threadIdx.x, lane = tid & 63, wid = tid >> 6;
    int wr = wid >> 1, wc = wid & 1, l15 = lane & 15, l4 = lane >> 4;
    int bz = blockIdx.z;
    const float*    Ab = atac + ((size_t)bz * KC_  + blockIdx.x * 128) * LMAX_;
    const _Float16* Bb = SB   + ((size_t)bz * FDIM_ + blockIdx.y * 128) * KPAD_;

    floatx4 acc[4][4];
    #pragma unroll
    for (int m = 0; m < 4; ++m)
        #pragma unroll
        for (int n = 0; n < 4; ++n)
            acc[m][n] = (floatx4){0.f, 0.f, 0.f, 0.f};

    for (int ch = 0; ch < KPAD_ / 64; ++ch) {
        int k0 = ch * 64;
        // stage A: 128 rows x 8 groups (8 f16 each), f32->f16 cvt, zero pad
        #pragma unroll
        for (int it = 0; it < 4; ++it) {
            int i = it * 256 + tid;
            int r = i >> 3, s = i & 7;
            int kg = k0 + s * 8;
            f16x8 o;
            if (kg < LMAX_) {              // 200%8==0 -> whole-group guard
                const float* p = Ab + (size_t)r * LMAX_ + kg;
                float4 v0 = *(const float4*)p;
                float4 v1 = *(const float4*)(p + 4);
                o[0] = (_Float16)v0.x; o[1] = (_Float16)v0.y;
                o[2] = (_Float16)v0.z; o[3] = (_Float16)v0.w;
                o[4] = (_Float16)v1.x; o[5] = (_Float16)v1.y;
                o[6] = (_Float16)v1.z; o[7] = (_Float16)v1.w;
            } else {
                #pragma unroll
                for (int j = 0; j < 8; ++j) o[j] = (_Float16)0.f;
            }
            *(f16x8*)&At[r * 64 + ((s ^ (r & 7)) << 3)] = o;
        }
        // stage B: f16 direct
        #pragma unroll
        for (int it = 0; it < 4; ++it) {
            int i = it * 256 + tid;
            int r = i >> 3, s = i & 7;
            f16x8 v = *(const f16x8*)(Bb + (size_t)r * KPAD_ + k0 + s * 8);
            *(f16x8*)&Bt[r * 64 + ((s ^ (r & 7)) << 3)] = v;
        }
        __syncthreads();
        #pragma unroll
        for (int ks = 0; ks < 2; ++ks) {
            f16x8 av[4], bv[4];
            #pragma unroll
            for (int m = 0; m < 4; ++m) {
                int row = wr * 64 + m * 16 + l15;
                av[m] = *(const f16x8*)&At[row * 64 + (((ks * 4 + l4) ^ (row & 7)) << 3)];
            }
            #pragma unroll
            for (int n = 0; n < 4; ++n) {
                int row = wc * 64 + n * 16 + l15;
                bv[n] = *(const f16x8*)&Bt[row * 64 + (((ks * 4 + l4) ^ (row & 7)) << 3)];
            }
            #pragma unroll
            for (int m = 0; m < 4; ++m)
                #pragma unroll
                for (int n = 0; n < 4; ++n)
                    acc[m][n] = __builtin_amdgcn_mfma_f32_16x16x32_f16(
                        av[m], bv[n], acc[m][n], 0, 0, 0);
        }
        __syncthreads();
    }

    int rb = blockIdx.x * 128 + wr * 64;
    int cb = blockIdx.y * 128 + wc * 64;
    _Float16* Qp = Q + (size_t)bz * KC_ * FDIM_;
    #pragma unroll
    for (int m = 0; m < 4; ++m)
        #pragma unroll
        for (int n = 0; n < 4; ++n)
            #pragma unroll
            for (int q = 0; q < 4; ++q)
                Qp[(size_t)(rb + m * 16 + l4 * 4 + q) * FDIM_ + cb + n * 16 + l15] =
                    (_Float16)acc[m][n][q];
}

// ---------------------------------------------------------------------------
// K4: fused MLP. Per block: 64 rows of M=16384.
//   h = relu(Q[64x512] @ W1^T + b1) -> LDS (f16, swizzled)
//   out = h @ W2^T + b2             -> global f32
// W1/W2 converted f32->f16 in-stage. 4 waves.
// ---------------------------------------------------------------------------
__global__ __launch_bounds__(256) void k_mlp(
    const _Float16* __restrict__ Q, const float* __restrict__ W1,
    const float* __restrict__ b1, const float* __restrict__ W2,
    const float* __restrict__ b2, float* __restrict__ out)
{
    __shared__ _Float16 Qt[64 * 64];      // 8 KB
    __shared__ _Float16 Wt[128 * 64];     // 16 KB
    __shared__ _Float16 Ht[64 * 128];     // 16 KB
    __shared__ _Float16 W2t[64 * 128];    // 16 KB

    int tid = threadIdx.x, lane = tid & 63, wid = tid >> 6;
    int wr = wid >> 1, wc = wid & 1, l15 = lane & 15, l4 = lane >> 4;
    size_t row0 = (size_t)blockIdx.x * 64;

    // stage W2 once: 64 rows x 16 groups
    #pragma unroll
    for (int it = 0; it < 4; ++it) {
        int i = it * 256 + tid;
        int r = i >> 4, s = i & 15;
        const float* p = W2 + r * 128 + s * 8;
        float4 v0 = *(const float4*)p;
        float4 v1 = *(const float4*)(p + 4);
        f16x8 o;
        o[0] = (_Float16)v0.x; o[1] = (_Float16)v0.y;
        o[2] = (_Float16)v0.z; o[3] = (_Float16)v0.w;
        o[4] = (_Float16)v1.x; o[5] = (_Float16)v1.y;
        o[6] = (_Float16)v1.z; o[7] = (_Float16)v1.w;
        *(f16x8*)&W2t[r * 128 + ((s ^ (r & 7)) << 3)] = o;
    }

    floatx4 acc[2][4];
    #pragma unroll
    for (int m = 0; m < 2; ++m)
        #pragma unroll
        for (int n = 0; n < 4; ++n)
            acc[m][n] = (floatx4){0.f, 0.f, 0.f, 0.f};

    for (int ch = 0; ch < 8; ++ch) {
        int k0 = ch * 64;
        // Q chunk: 64 rows x 8 groups (f16)
        #pragma unroll
        for (int it = 0; it < 2; ++it) {
            int i = it * 256 + tid;
            int r = i >> 3, s = i & 7;
            f16x8 v = *(const f16x8*)(Q + (row0 + r) * 512 + k0 + s * 8);
            *(f16x8*)&Qt[r * 64 + ((s ^ (r & 7)) << 3)] = v;
        }
        // W1 chunk: 128 rows x 8 groups (f32->f16)
        #pragma unroll
        for (int it = 0; it < 4; ++it) {
            int i = it * 256 + tid;
            int r = i >> 3, s = i & 7;
            const float* p = W1 + (size_t)r * 512 + k0 + s * 8;
            float4 v0 = *(const float4*)p;
            float4 v1 = *(const float4*)(p + 4);
            f16x8 o;
            o[0] = (_Float16)v0.x; o[1] = (_Float16)v0.y;
            o[2] = (_Float16)v0.z; o[3] = (_Float16)v0.w;
            o[4] = (_Float16)v1.x; o[5] = (_Float16)v1.y;
            o[6] = (_Float16)v1.z; o[7] = (_Float16)v1.w;
            *(f16x8*)&Wt[r * 64 + ((s ^ (r & 7)) << 3)] = o;
        }
        __syncthreads();
        #pragma unroll
        for (int ks = 0; ks < 2; ++ks) {
            f16x8 av[2], bv[4];
            #pragma unroll
            for (int m = 0; m < 2; ++m) {
                int row = wr * 32 + m * 16 + l15;
                av[m] = *(const f16x8*)&Qt[row * 64 + (((ks * 4 + l4) ^ (row & 7)) << 3)];
            }
            #pragma unroll
            for (int n = 0; n < 4; ++n) {
                int row = wc * 64 + n * 16 + l15;
                bv[n] = *(const f16x8*)&Wt[row * 64 + (((ks * 4 + l4) ^ (row & 7)) << 3)];
            }
            #pragma unroll
            for (int m = 0; m < 2; ++m)
                #pragma unroll
                for (int n = 0; n < 4; ++n)
                    acc[m][n] = __builtin_amdgcn_mfma_f32_16x16x32_f16(
                        av[m], bv[n], acc[m][n], 0, 0, 0);
        }
        __syncthreads();
    }

    // epilogue 1: relu(acc + b1) -> Ht[row][col], swizzled on 8-f16 groups
    #pragma unroll
    for (int n = 0; n < 4; ++n) {
        int col = wc * 64 + n * 16 + l15;
        float bb = b1[col];
        int colg = col >> 3, colw = col & 7;
        #pragma unroll
        for (int m = 0; m < 2; ++m) {
            #pragma unroll
            for (int q = 0; q < 4; ++q) {
                int row = wr * 32 + m * 16 + l4 * 4 + q;
                float v = fmaxf(acc[m][n][q] + bb, 0.f);
                Ht[row * 128 + ((colg ^ (row & 7)) << 3) + colw] = (_Float16)v;
            }
        }
    }
    __syncthreads();

    // MLP2: wave wid owns rows wid*16..+15; K=128 (4 slices), N=64 (4 frags)
    floatx4 acc2[4];
    #pragma unroll
    for (int n = 0; n < 4; ++n) acc2[n] = (floatx4){0.f, 0.f, 0.f, 0.f};
    #pragma unroll
    for (int ks = 0; ks < 4; ++ks) {
        int rowA = wid * 16 + l15;
        f16x8 a = *(const f16x8*)&Ht[rowA * 128 + (((ks * 4 + l4) ^ (rowA & 7)) << 3)];
        #pragma unroll
        for (int n = 0; n < 4; ++n) {
            int rowB = n * 16 + l15;
            f16x8 b = *(const f16x8*)&W2t[rowB * 128 + (((ks * 4 + l4) ^ (rowB & 7)) << 3)];
            acc2[n] = __builtin_amdgcn_mfma_f32_16x16x32_f16(a, b, acc2[n], 0, 0, 0);
        }
    }
    #pragma unroll
    for (int n = 0; n < 4; ++n) {
        float bb = b2[n * 16 + l15];
        #pragma unroll
        for (int q = 0; q < 4; ++q) {
            int row = wid * 16 + l4 * 4 + q;
            out[(row0 + row) * 64 + n * 16 + l15] = acc2[n][q] + bb;
        }
    }
}

// ---------------------------------------------------------------------------
extern "C" void kernel_launch(void* const* d_in, const int* in_sizes, int n_in,
                              void* d_out, int out_size, void* d_ws, size_t ws_size,
                              hipStream_t stream)
{
    const float* src  = (const float*)d_in[0];
    const float* prom = (const float*)d_in[1];
    const float* atac = (const float*)d_in[2];
    const float* mask = (const float*)d_in[3];
    const float* Wq_p = (const float*)d_in[4];
    const float* bq_p = (const float*)d_in[5];
    const float* Wq_e = (const float*)d_in[6];
    const float* bq_e = (const float*)d_in[7];
    const float* Wsig = (const float*)d_in[8];
    const float* bsig = (const float*)d_in[9];
    const float* W1   = (const float*)d_in[10];
    const float* b1   = (const float*)d_in[11];
    const float* W2   = (const float*)d_in[12];
    const float* b2   = (const float*)d_in[13];

    float* ws   = (float*)d_ws;
    float* Abuf = ws;                        // 16*512*33 = 270336 f32
    float* Cbuf = Abuf + 270336;             // 8192
    float* Pbuf = Cbuf + 8192;               // 8192
    _Float16* SB   = (_Float16*)(Pbuf + 8192);   // 16*512*256  = 2097152 f16
    _Float16* Qbuf = SB + 2097152;               // 16*1024*512 = 8388608 f16
    float* outp = (float*)d_out;

    hipLaunchKernelGGL(k_prep, dim3(512), dim3(256), 0, stream,
                       prom, Wq_p, bq_p, Wq_e, bq_e, Wsig, bsig, Abuf, Cbuf, Pbuf);

    hipLaunchKernelGGL(k_qk_ln, dim3(2048), dim3(256), 0, stream,
                       src, mask, Abuf, Cbuf, Pbuf, SB);

    // QKall[b,kcell,f] over l (padded to 256)
    hipLaunchKernelGGL(k_gemm_qk, dim3(8, 4, 16), dim3(256), 0, stream,
                       atac, SB, Qbuf);

    // out = relu(Q @ W1^T + b1) @ W2^T + b2
    hipLaunchKernelGGL(k_mlp, dim3(256), dim3(256), 0, stream,
                       Qbuf, W1, b1, W2, b2, outp);
}

// Round 5
// 63.271 us; speedup vs baseline: 3.4126x; 1.1400x over previous
//
#include <hip/hip_runtime.h>

#define B_ 16
#define FDIM_ 512
#define LMAX_ 200
#define KC_ 1024
#define KPAD_ 256

typedef __attribute__((ext_vector_type(8)))  _Float16 f16x8;
typedef __attribute__((ext_vector_type(4)))  float    floatx4;

// ---------------------------------------------------------------------------
// K1: one block per f (512 blocks). LDS-staged small-matrix prep.
//   pq[b][k] = prom[b]·Wq_p[f*32+k] + bq_p ; A[b][j] = sum_k pq*Wq_e ;
//   C[b] = sum_k pq*bq_e ; P[b] = sum_k pq*Wsig + bsig
// ---------------------------------------------------------------------------
__global__ __launch_bounds__(256) void k_prep(
    const float* __restrict__ prom, const float* __restrict__ Wq_p,
    const float* __restrict__ bq_p, const float* __restrict__ Wq_e,
    const float* __restrict__ bq_e, const float* __restrict__ Wsig,
    const float* __restrict__ bsig,
    float* __restrict__ Aout, float* __restrict__ Cout, float* __restrict__ Pout)
{
    int f = blockIdx.x;
    int tid = threadIdx.x;

    __shared__ float Wp[32][33];
    __shared__ float We[32][33];
    __shared__ float promS[16][32];
    __shared__ float pqS[16][33];
    __shared__ float bqpS[32], bqeS[32], wsigS[32];

    for (int i = tid; i < 1024; i += 256)
        Wp[i >> 5][i & 31] = Wq_p[(size_t)f * 1024 + i];
    if (tid < 128) ((float4*)&promS[0][0])[tid] = ((const float4*)prom)[tid];
    for (int i = tid; i < 32 * 33; i += 256) {
        int k = i / 33, j = i - k * 33;
        We[k][j] = Wq_e[((size_t)(k * 512 + f)) * 33 + j];
    }
    if (tid < 32) {
        bqpS[tid]  = bq_p[f * 32 + tid];
        bqeS[tid]  = bq_e[tid * 512 + f];
        wsigS[tid] = Wsig[tid];
    }
    __syncthreads();

    for (int i = tid; i < 512; i += 256) {
        int b = i >> 5, k = i & 31;
        float s = bqpS[k];
        #pragma unroll
        for (int j = 0; j < 32; ++j) s += promS[b][j] * Wp[k][j];
        pqS[b][k] = s;
    }
    __syncthreads();

    for (int i = tid; i < 16 * 33; i += 256) {
        int b = i / 33, j = i - b * 33;
        float s = 0.f;
        #pragma unroll
        for (int k = 0; k < 32; ++k) s += pqS[b][k] * We[k][j];
        Aout[((size_t)(b * 512 + f)) * 33 + j] = s;
    }
    if (tid < 16) {
        int b = tid;
        float c = 0.f, p = bsig[0];
        #pragma unroll
        for (int k = 0; k < 32; ++k) {
            c += pqS[b][k] * bqeS[k];
            p += pqS[b][k] * wsigS[k];
        }
        Cout[b * 512 + f] = c;
        Pout[b * 512 + f] = p;
    }
}

// ---------------------------------------------------------------------------
// K2 v2: block per (b, f-chunk of 8). src[b] staged once in LDS (flat, the
// (33l+j)%32 bank pattern is conflict-free). Thread = (f_sub=tid>>5, l=tid&31
// + 32t). Lanes sweep l -> coalesced SB writes. LN reduce via 32-lane shfl.
// SB stride 256: S[0]=P, S[1..199]=normed, S[200..255]=0.
// ---------------------------------------------------------------------------
__global__ __launch_bounds__(256) void k_qk_ln(
    const float* __restrict__ src, const float* __restrict__ mask,
    const float* __restrict__ A, const float* __restrict__ C,
    const float* __restrict__ P, _Float16* __restrict__ SB)
{
    __shared__ float srcF[6600];        // 200*33
    __shared__ float maskS[200];

    int tid = threadIdx.x;
    int b = blockIdx.x >> 6;
    int fc = blockIdx.x & 63;
    int f_sub = tid >> 5, l_loc = tid & 31;
    int f = fc * 8 + f_sub;
    int wid = b * 512 + f;

    for (int i = tid; i < 6600; i += 256) srcF[i] = src[(size_t)b * 6600 + i];
    for (int i = tid; i < 200; i += 256)  maskS[i] = mask[b * 200 + i];

    float Ar[33];
    const float* Ap = A + (size_t)wid * 33;
    #pragma unroll
    for (int j = 0; j < 33; ++j) Ar[j] = Ap[j];
    float Cv = C[wid], Pv = P[wid];
    __syncthreads();

    float vals[8];
    float s1 = 0.f, s2 = 0.f;
    #pragma unroll
    for (int t = 0; t < 8; ++t) {
        int l = l_loc + 32 * t;
        float v = 0.f;
        if (l < LMAX_) {
            const float* sp = &srcF[l * 33];
            float s = Cv;
            #pragma unroll
            for (int j = 0; j < 33; ++j) s += sp[j] * Ar[j];
            v = s * maskS[l];
            if (l >= 1) { s1 += v; s2 += v * v; }
        }
        vals[t] = v;
    }
    // reduce over the 32 l-lanes sharing f (xor<32 stays in half-wave)
    #pragma unroll
    for (int off = 16; off > 0; off >>= 1) {
        s1 += __shfl_xor(s1, off, 64);
        s2 += __shfl_xor(s2, off, 64);
    }
    float mu  = s1 * (1.f / 199.f);
    float var = s2 * (1.f / 199.f) - mu * mu;
    float inv = 1.0f / sqrtf(var + 1e-5f);

    _Float16* Sp = SB + (size_t)wid * KPAD_;
    #pragma unroll
    for (int t = 0; t < 8; ++t) {
        int l = l_loc + 32 * t;
        float v = (l == 0) ? Pv : ((l < LMAX_) ? (vals[t] - mu) * inv : 0.f);
        Sp[l] = (_Float16)v;
    }
}

// ---------------------------------------------------------------------------
// K3: fused QKall-GEMM + MLP megakernel. Block = 64 kcell rows x full f=512.
// 4 waves: QK wave tile 64x128 (acc 4x8), BK=64, K=256 (zeros inert).
// Q-tile (64x512 f16) written to LDS (aliases dead B-buffer) -> MLP1
// (W1 chunk-staged f32->f16) -> relu -> Ht -> MLP2 (W2 LDS-resident) -> out.
// All LDS tiles XOR-swizzled on 8-f16 groups: g ^= row&7.
// ---------------------------------------------------------------------------
__global__ __launch_bounds__(256) void k_fused(
    const float* __restrict__ atac, const _Float16* __restrict__ SB,
    const float* __restrict__ W1, const float* __restrict__ b1,
    const float* __restrict__ W2, const float* __restrict__ b2,
    float* __restrict__ out)
{
    // LDS layout (f16 elems): At 4096 | Wt 8192 | W2t 8192 | Ht 8192 | Bt/Qt 32768
    __shared__ _Float16 lds[61440];     // 120 KB
    _Float16* At  = lds;
    _Float16* Wt  = lds + 4096;
    _Float16* W2t = lds + 12288;
    _Float16* Ht  = lds + 20480;
    _Float16* Bt  = lds + 28672;
    _Float16* Qt  = Bt;                 // alias: Bt dead after QK phase

    int tid = threadIdx.x, lane = tid & 63, wid = tid >> 6;
    int l15 = lane & 15, l4 = lane >> 4;
    int b = blockIdx.x >> 4;
    int row0 = (blockIdx.x & 15) * 64;

    const float*    Ab = atac + ((size_t)b * KC_ + row0) * LMAX_;
    const _Float16* Bb = SB + (size_t)b * FDIM_ * KPAD_;

    // stage W2 once: 64 rows x 16 groups, f32->f16
    #pragma unroll
    for (int it = 0; it < 4; ++it) {
        int i = it * 256 + tid;
        int r = i >> 4, s = i & 15;
        const float* p = W2 + r * 128 + s * 8;
        float4 v0 = *(const float4*)p;
        float4 v1 = *(const float4*)(p + 4);
        f16x8 o;
        o[0] = (_Float16)v0.x; o[1] = (_Float16)v0.y;
        o[2] = (_Float16)v0.z; o[3] = (_Float16)v0.w;
        o[4] = (_Float16)v1.x; o[5] = (_Float16)v1.y;
        o[6] = (_Float16)v1.z; o[7] = (_Float16)v1.w;
        *(f16x8*)&W2t[r * 128 + ((s ^ (r & 7)) << 3)] = o;
    }

    // ---------------- phase 1: QK GEMM (64 x 512, K=256) ----------------
    floatx4 acc[4][8];
    #pragma unroll
    for (int m = 0; m < 4; ++m)
        #pragma unroll
        for (int n = 0; n < 8; ++n)
            acc[m][n] = (floatx4){0.f, 0.f, 0.f, 0.f};

    for (int ch = 0; ch < 4; ++ch) {
        int k0 = ch * 64;
        // A: 64 rows x 8 groups, f32->f16, zero-pad l>=200
        #pragma unroll
        for (int it = 0; it < 2; ++it) {
            int i = it * 256 + tid;
            int r = i >> 3, s = i & 7;
            int kg = k0 + s * 8;
            f16x8 o;
            if (kg < LMAX_) {
                const float* p = Ab + (size_t)r * LMAX_ + kg;
                float4 v0 = *(const float4*)p;
                float4 v1 = *(const float4*)(p + 4);
                o[0] = (_Float16)v0.x; o[1] = (_Float16)v0.y;
                o[2] = (_Float16)v0.z; o[3] = (_Float16)v0.w;
                o[4] = (_Float16)v1.x; o[5] = (_Float16)v1.y;
                o[6] = (_Float16)v1.z; o[7] = (_Float16)v1.w;
            } else {
                #pragma unroll
                for (int j = 0; j < 8; ++j) o[j] = (_Float16)0.f;
            }
            *(f16x8*)&At[r * 64 + ((s ^ (r & 7)) << 3)] = o;
        }
        // B: 512 f-rows x 8 groups (f16 direct)
        #pragma unroll
        for (int it = 0; it < 16; ++it) {
            int i = it * 256 + tid;
            int r = i >> 3, s = i & 7;
            f16x8 v = *(const f16x8*)(Bb + (size_t)r * KPAD_ + k0 + s * 8);
            *(f16x8*)&Bt[r * 64 + ((s ^ (r & 7)) << 3)] = v;
        }
        __syncthreads();
        #pragma unroll
        for (int ks = 0; ks < 2; ++ks) {
            f16x8 av[4], bv[8];
            #pragma unroll
            for (int m = 0; m < 4; ++m) {
                int row = m * 16 + l15;
                av[m] = *(const f16x8*)&At[row * 64 + (((ks * 4 + l4) ^ (row & 7)) << 3)];
            }
            #pragma unroll
            for (int n = 0; n < 8; ++n) {
                int frow = wid * 128 + n * 16 + l15;
                bv[n] = *(const f16x8*)&Bt[frow * 64 + (((ks * 4 + l4) ^ (frow & 7)) << 3)];
            }
            #pragma unroll
            for (int m = 0; m < 4; ++m)
                #pragma unroll
                for (int n = 0; n < 8; ++n)
                    acc[m][n] = __builtin_amdgcn_mfma_f32_16x16x32_f16(
                        av[m], bv[n], acc[m][n], 0, 0, 0);
        }
        __syncthreads();
    }

    // acc -> Qt (64 x 512 f16, swizzled). Bt is dead (barrier above).
    #pragma unroll
    for (int m = 0; m < 4; ++m) {
        #pragma unroll
        for (int n = 0; n < 8; ++n) {
            int fcol = wid * 128 + n * 16 + l15;
            int g = fcol >> 3, w = fcol & 7;
            #pragma unroll
            for (int q = 0; q < 4; ++q) {
                int row = m * 16 + l4 * 4 + q;
                Qt[row * 512 + ((g ^ (row & 7)) << 3) + w] = (_Float16)acc[m][n][q];
            }
        }
    }
    __syncthreads();

    // ---------------- phase 2: MLP1 h = relu(Q @ W1^T + b1) ----------------
    floatx4 acc2[8];
    #pragma unroll
    for (int n = 0; n < 8; ++n) acc2[n] = (floatx4){0.f, 0.f, 0.f, 0.f};

    for (int ch = 0; ch < 8; ++ch) {
        int k0 = ch * 64;
        // W1 chunk: 128 rows x 8 groups, f32->f16
        #pragma unroll
        for (int it = 0; it < 4; ++it) {
            int i = it * 256 + tid;
            int r = i >> 3, s = i & 7;
            const float* p = W1 + (size_t)r * 512 + k0 + s * 8;
            float4 v0 = *(const float4*)p;
            float4 v1 = *(const float4*)(p + 4);
            f16x8 o;
            o[0] = (_Float16)v0.x; o[1] = (_Float16)v0.y;
            o[2] = (_Float16)v0.z; o[3] = (_Float16)v0.w;
            o[4] = (_Float16)v1.x; o[5] = (_Float16)v1.y;
            o[6] = (_Float16)v1.z; o[7] = (_Float16)v1.w;
            *(f16x8*)&Wt[r * 64 + ((s ^ (r & 7)) << 3)] = o;
        }
        __syncthreads();
        #pragma unroll
        for (int ks = 0; ks < 2; ++ks) {
            int arow = wid * 16 + l15;
            int gk = ch * 8 + ks * 4 + l4;
            f16x8 a = *(const f16x8*)&Qt[arow * 512 + ((gk ^ (arow & 7)) << 3)];
            #pragma unroll
            for (int n = 0; n < 8; ++n) {
                int brow = n * 16 + l15;
                f16x8 bw = *(const f16x8*)&Wt[brow * 64 + (((ks * 4 + l4) ^ (brow & 7)) << 3)];
                acc2[n] = __builtin_amdgcn_mfma_f32_16x16x32_f16(a, bw, acc2[n], 0, 0, 0);
            }
        }
        __syncthreads();
    }

    // relu(acc2 + b1) -> Ht (64 x 128, swizzled)
    #pragma unroll
    for (int n = 0; n < 8; ++n) {
        int col = n * 16 + l15;
        float bb = b1[col];
        int cg = col >> 3, cw = col & 7;
        #pragma unroll
        for (int q = 0; q < 4; ++q) {
            int row = wid * 16 + l4 * 4 + q;
            float v = fmaxf(acc2[n][q] + bb, 0.f);
            Ht[row * 128 + ((cg ^ (row & 7)) << 3) + cw] = (_Float16)v;
        }
    }
    __syncthreads();

    // ---------------- phase 3: MLP2 out = h @ W2^T + b2 ----------------
    floatx4 acc3[4];
    #pragma unroll
    for (int n = 0; n < 4; ++n) acc3[n] = (floatx4){0.f, 0.f, 0.f, 0.f};
    #pragma unroll
    for (int ks = 0; ks < 4; ++ks) {
        int arow = wid * 16 + l15;
        f16x8 a = *(const f16x8*)&Ht[arow * 128 + (((ks * 4 + l4) ^ (arow & 7)) << 3)];
        #pragma unroll
        for (int n = 0; n < 4; ++n) {
            int brow = n * 16 + l15;
            f16x8 bw = *(const f16x8*)&W2t[brow * 128 + (((ks * 4 + l4) ^ (brow & 7)) << 3)];
            acc3[n] = __builtin_amdgcn_mfma_f32_16x16x32_f16(a, bw, acc3[n], 0, 0, 0);
        }
    }
    #pragma unroll
    for (int n = 0; n < 4; ++n) {
        float bb = b2[n * 16 + l15];
        #pragma unroll
        for (int q = 0; q < 4; ++q) {
            size_t grow = (size_t)b * KC_ + row0 + wid * 16 + l4 * 4 + q;
            out[grow * 64 + n * 16 + l15] = acc3[n][q] + bb;
        }
    }
}

// ---------------------------------------------------------------------------
extern "C" void kernel_launch(void* const* d_in, const int* in_sizes, int n_in,
                              void* d_out, int out_size, void* d_ws, size_t ws_size,
                              hipStream_t stream)
{
    const float* src  = (const float*)d_in[0];
    const float* prom = (const float*)d_in[1];
    const float* atac = (const float*)d_in[2];
    const float* mask = (const float*)d_in[3];
    const float* Wq_p = (const float*)d_in[4];
    const float* bq_p = (const float*)d_in[5];
    const float* Wq_e = (const float*)d_in[6];
    const float* bq_e = (const float*)d_in[7];
    const float* Wsig = (const float*)d_in[8];
    const float* bsig = (const float*)d_in[9];
    const float* W1   = (const float*)d_in[10];
    const float* b1   = (const float*)d_in[11];
    const float* W2   = (const float*)d_in[12];
    const float* b2   = (const float*)d_in[13];

    float* ws   = (float*)d_ws;
    float* Abuf = ws;                        // 16*512*33 = 270336 f32
    float* Cbuf = Abuf + 270336;             // 8192
    float* Pbuf = Cbuf + 8192;               // 8192
    _Float16* SB = (_Float16*)(Pbuf + 8192); // 16*512*256 = 2097152 f16
    float* outp = (float*)d_out;

    hipLaunchKernelGGL(k_prep, dim3(512), dim3(256), 0, stream,
                       prom, Wq_p, bq_p, Wq_e, bq_e, Wsig, bsig, Abuf, Cbuf, Pbuf);

    hipLaunchKernelGGL(k_qk_ln, dim3(1024), dim3(256), 0, stream,
                       src, mask, Abuf, Cbuf, Pbuf, SB);

    hipLaunchKernelGGL(k_fused, dim3(256), dim3(256), 0, stream,
                       atac, SB, W1, b1, W2, b2, outp);
}

// Round 6
// 58.037 us; speedup vs baseline: 3.7203x; 1.0902x over previous
//
#include <hip/hip_runtime.h>

#define B_ 16
#define FDIM_ 512
#define LMAX_ 200
#define KC_ 1024
#define KPAD_ 256

typedef __attribute__((ext_vector_type(8)))  _Float16 f16x8;
typedef __attribute__((ext_vector_type(4)))  float    floatx4;

__device__ __forceinline__ f16x8 ld8f(const float* __restrict__ p) {
    float4 v0 = *(const float4*)p;
    float4 v1 = *(const float4*)(p + 4);
    f16x8 o;
    o[0] = (_Float16)v0.x; o[1] = (_Float16)v0.y;
    o[2] = (_Float16)v0.z; o[3] = (_Float16)v0.w;
    o[4] = (_Float16)v1.x; o[5] = (_Float16)v1.y;
    o[6] = (_Float16)v1.z; o[7] = (_Float16)v1.w;
    return o;
}

// ---------------------------------------------------------------------------
// K1: one block per f (512 blocks). LDS-staged small-matrix prep.
// ---------------------------------------------------------------------------
__global__ __launch_bounds__(256) void k_prep(
    const float* __restrict__ prom, const float* __restrict__ Wq_p,
    const float* __restrict__ bq_p, const float* __restrict__ Wq_e,
    const float* __restrict__ bq_e, const float* __restrict__ Wsig,
    const float* __restrict__ bsig,
    float* __restrict__ Aout, float* __restrict__ Cout, float* __restrict__ Pout)
{
    int f = blockIdx.x;
    int tid = threadIdx.x;

    __shared__ float Wp[32][33];
    __shared__ float We[32][33];
    __shared__ float promS[16][32];
    __shared__ float pqS[16][33];
    __shared__ float bqpS[32], bqeS[32], wsigS[32];

    for (int i = tid; i < 1024; i += 256)
        Wp[i >> 5][i & 31] = Wq_p[(size_t)f * 1024 + i];
    if (tid < 128) ((float4*)&promS[0][0])[tid] = ((const float4*)prom)[tid];
    for (int i = tid; i < 32 * 33; i += 256) {
        int k = i / 33, j = i - k * 33;
        We[k][j] = Wq_e[((size_t)(k * 512 + f)) * 33 + j];
    }
    if (tid < 32) {
        bqpS[tid]  = bq_p[f * 32 + tid];
        bqeS[tid]  = bq_e[tid * 512 + f];
        wsigS[tid] = Wsig[tid];
    }
    __syncthreads();

    for (int i = tid; i < 512; i += 256) {
        int b = i >> 5, k = i & 31;
        float s = bqpS[k];
        #pragma unroll
        for (int j = 0; j < 32; ++j) s += promS[b][j] * Wp[k][j];
        pqS[b][k] = s;
    }
    __syncthreads();

    for (int i = tid; i < 16 * 33; i += 256) {
        int b = i / 33, j = i - b * 33;
        float s = 0.f;
        #pragma unroll
        for (int k = 0; k < 32; ++k) s += pqS[b][k] * We[k][j];
        Aout[((size_t)(b * 512 + f)) * 33 + j] = s;
    }
    if (tid < 16) {
        int b = tid;
        float c = 0.f, p = bsig[0];
        #pragma unroll
        for (int k = 0; k < 32; ++k) {
            c += pqS[b][k] * bqeS[k];
            p += pqS[b][k] * wsigS[k];
        }
        Cout[b * 512 + f] = c;
        Pout[b * 512 + f] = p;
    }
}

// ---------------------------------------------------------------------------
// K2: block per (b, f-chunk of 8). src[b] staged once in LDS.
// SB stride 256: S[0]=P, S[1..199]=normed, S[200..255]=0.
// ---------------------------------------------------------------------------
__global__ __launch_bounds__(256) void k_qk_ln(
    const float* __restrict__ src, const float* __restrict__ mask,
    const float* __restrict__ A, const float* __restrict__ C,
    const float* __restrict__ P, _Float16* __restrict__ SB)
{
    __shared__ float srcF[6600];        // 200*33
    __shared__ float maskS[200];

    int tid = threadIdx.x;
    int b = blockIdx.x >> 6;
    int fc = blockIdx.x & 63;
    int f_sub = tid >> 5, l_loc = tid & 31;
    int f = fc * 8 + f_sub;
    int wid = b * 512 + f;

    for (int i = tid; i < 6600; i += 256) srcF[i] = src[(size_t)b * 6600 + i];
    for (int i = tid; i < 200; i += 256)  maskS[i] = mask[b * 200 + i];

    float Ar[33];
    const float* Ap = A + (size_t)wid * 33;
    #pragma unroll
    for (int j = 0; j < 33; ++j) Ar[j] = Ap[j];
    float Cv = C[wid], Pv = P[wid];
    __syncthreads();

    float vals[8];
    float s1 = 0.f, s2 = 0.f;
    #pragma unroll
    for (int t = 0; t < 8; ++t) {
        int l = l_loc + 32 * t;
        float v = 0.f;
        if (l < LMAX_) {
            const float* sp = &srcF[l * 33];
            float s = Cv;
            #pragma unroll
            for (int j = 0; j < 33; ++j) s += sp[j] * Ar[j];
            v = s * maskS[l];
            if (l >= 1) { s1 += v; s2 += v * v; }
        }
        vals[t] = v;
    }
    #pragma unroll
    for (int off = 16; off > 0; off >>= 1) {
        s1 += __shfl_xor(s1, off, 64);
        s2 += __shfl_xor(s2, off, 64);
    }
    float mu  = s1 * (1.f / 199.f);
    float var = s2 * (1.f / 199.f) - mu * mu;
    float inv = 1.0f / sqrtf(var + 1e-5f);

    _Float16* Sp = SB + (size_t)wid * KPAD_;
    #pragma unroll
    for (int t = 0; t < 8; ++t) {
        int l = l_loc + 32 * t;
        float v = (l == 0) ? Pv : ((l < LMAX_) ? (vals[t] - mu) * inv : 0.f);
        Sp[l] = (_Float16)v;
    }
}

// ---------------------------------------------------------------------------
// K3 v2: fused QK-GEMM + MLP, latency-oriented.
// Block = 64 kcell rows x full f=512, 4 waves, 2 blocks/CU (80 KB LDS).
// Phase 1 (no LDS, no barriers): acc[4][8]; A direct from atac (f32->f16,
//   guard k>=200), B direct from SB f16 (L2-hot). Wave owns f-cols wid*128.
// Qt (64x512 f16 swizzled) <- acc; barrier.
// Phase 2: wave owns 32 h-cols x all 64 rows; A from Qt, B=W1 direct global
//   (f32->f16, read exactly once per block). relu+b1 -> Ht; barrier.
// Phase 3: wave owns 16 rows; A from Ht, B=W2 direct global. out f32.
// ---------------------------------------------------------------------------
__global__ __launch_bounds__(256, 2) void k_fused(
    const float* __restrict__ atac, const _Float16* __restrict__ SB,
    const float* __restrict__ W1, const float* __restrict__ b1,
    const float* __restrict__ W2, const float* __restrict__ b2,
    float* __restrict__ out)
{
    __shared__ _Float16 lds[40960];     // 80 KB: Qt 32768 | Ht 8192
    _Float16* Qt = lds;
    _Float16* Ht = lds + 32768;

    int tid = threadIdx.x, lane = tid & 63, wid = tid >> 6;
    int l15 = lane & 15, l4 = lane >> 4;
    int b = blockIdx.x >> 4;
    int row0 = (blockIdx.x & 15) * 64;

    const float*    Ab = atac + ((size_t)b * KC_ + row0) * LMAX_;
    const _Float16* Bb = SB + (size_t)b * FDIM_ * KPAD_;

    // ---------------- phase 1: QK GEMM (64 x 512, K=256), no LDS ----------
    floatx4 acc[4][8];
    #pragma unroll
    for (int m = 0; m < 4; ++m)
        #pragma unroll
        for (int n = 0; n < 8; ++n)
            acc[m][n] = (floatx4){0.f, 0.f, 0.f, 0.f};

    #pragma unroll
    for (int ks = 0; ks < 8; ++ks) {
        int kg = ks * 32 + l4 * 8;
        bool inr = kg < LMAX_;          // 200 % 8 == 0: whole group in/out
        f16x8 av[4], bv[8];
        #pragma unroll
        for (int m = 0; m < 4; ++m) {
            if (inr) {
                av[m] = ld8f(Ab + (size_t)(m * 16 + l15) * LMAX_ + kg);
            } else {
                #pragma unroll
                for (int j = 0; j < 8; ++j) av[m][j] = (_Float16)0.f;
            }
        }
        #pragma unroll
        for (int n = 0; n < 8; ++n)
            bv[n] = *(const f16x8*)(Bb + (size_t)(wid * 128 + n * 16 + l15) * KPAD_ + kg);
        #pragma unroll
        for (int m = 0; m < 4; ++m)
            #pragma unroll
            for (int n = 0; n < 8; ++n)
                acc[m][n] = __builtin_amdgcn_mfma_f32_16x16x32_f16(
                    av[m], bv[n], acc[m][n], 0, 0, 0);
    }

    // acc -> Qt (64 x 512 f16, swizzled on 8-f16 groups: g ^= row&7)
    #pragma unroll
    for (int m = 0; m < 4; ++m) {
        #pragma unroll
        for (int n = 0; n < 8; ++n) {
            int fcol = wid * 128 + n * 16 + l15;
            int g = fcol >> 3, w = fcol & 7;
            #pragma unroll
            for (int q = 0; q < 4; ++q) {
                int row = m * 16 + l4 * 4 + q;
                Qt[row * 512 + ((g ^ (row & 7)) << 3) + w] = (_Float16)acc[m][n][q];
            }
        }
    }
    __syncthreads();

    // ---------------- phase 2: MLP1, wave owns h-cols wid*32..+31 ----------
    floatx4 acc2[4][2];
    #pragma unroll
    for (int m = 0; m < 4; ++m)
        #pragma unroll
        for (int n = 0; n < 2; ++n)
            acc2[m][n] = (floatx4){0.f, 0.f, 0.f, 0.f};

    #pragma unroll
    for (int ks = 0; ks < 16; ++ks) {
        int g = ks * 4 + l4;
        f16x8 av[4], bv[2];
        #pragma unroll
        for (int m = 0; m < 4; ++m) {
            int row = m * 16 + l15;
            av[m] = *(const f16x8*)&Qt[row * 512 + ((g ^ (row & 7)) << 3)];
        }
        #pragma unroll
        for (int n = 0; n < 2; ++n)
            bv[n] = ld8f(W1 + (size_t)(wid * 32 + n * 16 + l15) * 512 + ks * 32 + l4 * 8);
        #pragma unroll
        for (int m = 0; m < 4; ++m)
            #pragma unroll
            for (int n = 0; n < 2; ++n)
                acc2[m][n] = __builtin_amdgcn_mfma_f32_16x16x32_f16(
                    av[m], bv[n], acc2[m][n], 0, 0, 0);
    }

    // relu(acc2 + b1) -> Ht (64 x 128, swizzled)
    #pragma unroll
    for (int n = 0; n < 2; ++n) {
        int col = wid * 32 + n * 16 + l15;
        float bb = b1[col];
        int cg = col >> 3, cw = col & 7;
        #pragma unroll
        for (int m = 0; m < 4; ++m) {
            #pragma unroll
            for (int q = 0; q < 4; ++q) {
                int row = m * 16 + l4 * 4 + q;
                float v = fmaxf(acc2[m][n][q] + bb, 0.f);
                Ht[row * 128 + ((cg ^ (row & 7)) << 3) + cw] = (_Float16)v;
            }
        }
    }
    __syncthreads();

    // ---------------- phase 3: MLP2, wave owns rows wid*16..+15 ------------
    floatx4 acc3[4];
    #pragma unroll
    for (int n = 0; n < 4; ++n) acc3[n] = (floatx4){0.f, 0.f, 0.f, 0.f};
    #pragma unroll
    for (int ks = 0; ks < 4; ++ks) {
        int g = ks * 4 + l4;
        int arow = wid * 16 + l15;
        f16x8 a = *(const f16x8*)&Ht[arow * 128 + ((g ^ (arow & 7)) << 3)];
        #pragma unroll
        for (int n = 0; n < 4; ++n) {
            f16x8 bw = ld8f(W2 + (size_t)(n * 16 + l15) * 128 + ks * 32 + l4 * 8);
            acc3[n] = __builtin_amdgcn_mfma_f32_16x16x32_f16(a, bw, acc3[n], 0, 0, 0);
        }
    }
    #pragma unroll
    for (int n = 0; n < 4; ++n) {
        float bb = b2[n * 16 + l15];
        #pragma unroll
        for (int q = 0; q < 4; ++q) {
            size_t grow = (size_t)b * KC_ + row0 + wid * 16 + l4 * 4 + q;
            out[grow * 64 + n * 16 + l15] = acc3[n][q] + bb;
        }
    }
}

// ---------------------------------------------------------------------------
extern "C" void kernel_launch(void* const* d_in, const int* in_sizes, int n_in,
                              void* d_out, int out_size, void* d_ws, size_t ws_size,
                              hipStream_t stream)
{
    const float* src  = (const float*)d_in[0];
    const float* prom = (const float*)d_in[1];
    const float* atac = (const float*)d_in[2];
    const float* mask = (const float*)d_in[3];
    const float* Wq_p = (const float*)d_in[4];
    const float* bq_p = (const float*)d_in[5];
    const float* Wq_e = (const float*)d_in[6];
    const float* bq_e = (const float*)d_in[7];
    const float* Wsig = (const float*)d_in[8];
    const float* bsig = (const float*)d_in[9];
    const float* W1   = (const float*)d_in[10];
    const float* b1   = (const float*)d_in[11];
    const float* W2   = (const float*)d_in[12];
    const float* b2   = (const float*)d_in[13];

    float* ws   = (float*)d_ws;
    float* Abuf = ws;                        // 16*512*33 = 270336 f32
    float* Cbuf = Abuf + 270336;             // 8192
    float* Pbuf = Cbuf + 8192;               // 8192
    _Float16* SB = (_Float16*)(Pbuf + 8192); // 16*512*256 = 2097152 f16
    float* outp = (float*)d_out;

    hipLaunchKernelGGL(k_prep, dim3(512), dim3(256), 0, stream,
                       prom, Wq_p, bq_p, Wq_e, bq_e, Wsig, bsig, Abuf, Cbuf, Pbuf);

    hipLaunchKernelGGL(k_qk_ln, dim3(1024), dim3(256), 0, stream,
                       src, mask, Abuf, Cbuf, Pbuf, SB);

    hipLaunchKernelGGL(k_fused, dim3(256), dim3(256), 0, stream,
                       atac, SB, W1, b1, W2, b2, outp);
}

// Round 8
// 53.621 us; speedup vs baseline: 4.0267x; 1.0824x over previous
//
#include <hip/hip_runtime.h>

#define B_ 16
#define FDIM_ 512
#define LMAX_ 200
#define KC_ 1024
#define KPAD_ 256

typedef __attribute__((ext_vector_type(8)))  _Float16 f16x8;
typedef __attribute__((ext_vector_type(4)))  float    floatx4;

__device__ __forceinline__ f16x8 ld8f(const float* __restrict__ p) {
    float4 v0 = *(const float4*)p;
    float4 v1 = *(const float4*)(p + 4);
    f16x8 o;
    o[0] = (_Float16)v0.x; o[1] = (_Float16)v0.y;
    o[2] = (_Float16)v0.z; o[3] = (_Float16)v0.w;
    o[4] = (_Float16)v1.x; o[5] = (_Float16)v1.y;
    o[6] = (_Float16)v1.z; o[7] = (_Float16)v1.w;
    return o;
}

// ---------------------------------------------------------------------------
// K1 (merged prep + qk + ln): block per (b, f-chunk of 8). Grid 16*64=1024.
//   pq[fs][k] = prom[b]·Wq_p[f*32+k] + bq_p        (thread = (fs, k), 256 thr)
//   A[fs][j]  = sum_k pq*Wq_e[k*512+f][j]           (264 entries, strided loop)
//   C[fs], P[fs]                                    (threads 0..7)
//   then per (fs, l): QK = src[b,l]·A + C, *mask; LN over l=1..199;
//   SB stride 256: S[0]=P, S[1..199]=normed, S[200..255]=0.
// ---------------------------------------------------------------------------
__global__ __launch_bounds__(256) void k_qk(
    const float* __restrict__ src, const float* __restrict__ prom,
    const float* __restrict__ mask,
    const float* __restrict__ Wq_p, const float* __restrict__ bq_p,
    const float* __restrict__ Wq_e, const float* __restrict__ bq_e,
    const float* __restrict__ Wsig, const float* __restrict__ bsig,
    _Float16* __restrict__ SB)
{
    __shared__ float srcF[6600];        // 200*33
    __shared__ float maskS[200];
    __shared__ float promS[32];
    __shared__ float pqS[8][33];
    __shared__ float AS[8][34];
    __shared__ float CS[8], PS[8];

    int tid = threadIdx.x;
    int b  = blockIdx.x >> 6;
    int fc = blockIdx.x & 63;
    int f_sub = tid >> 5, l_loc = tid & 31;
    int f = fc * 8 + f_sub;

    for (int i = tid; i < 6600; i += 256) srcF[i] = src[(size_t)b * 6600 + i];
    for (int i = tid; i < 200; i += 256)  maskS[i] = mask[b * 200 + i];
    if (tid < 32) promS[tid] = prom[b * 32 + tid];
    __syncthreads();

    // pq: thread (f_sub, k=l_loc); Wq_p row f*32+k = fc*256+tid (coalesced rows)
    {
        int k = l_loc;
        const float4* wr4 = (const float4*)(Wq_p + (size_t)(f * 32 + k) * 32);
        float s = bq_p[f * 32 + k];
        #pragma unroll
        for (int j4 = 0; j4 < 8; ++j4) {
            float4 v = wr4[j4];
            s += promS[4 * j4 + 0] * v.x + promS[4 * j4 + 1] * v.y
               + promS[4 * j4 + 2] * v.z + promS[4 * j4 + 3] * v.w;
        }
        pqS[f_sub][k] = s;
    }
    __syncthreads();

    // A: 264 (fs,j) entries via strided loop (threads 0..7 take the overflow)
    for (int i = tid; i < 264; i += 256) {
        int fs = i / 33, j = i - fs * 33;
        int ff = fc * 8 + fs;
        float s = 0.f;
        #pragma unroll
        for (int k = 0; k < 32; ++k)
            s += pqS[fs][k] * Wq_e[((size_t)(k * 512 + ff)) * 33 + j];
        AS[fs][j] = s;
    }
    // C, P: threads 0..7
    if (tid < 8) {
        int fs = tid;
        int ff = fc * 8 + fs;
        float c = 0.f, p = bsig[0];
        #pragma unroll
        for (int k = 0; k < 32; ++k) {
            c += pqS[fs][k] * bq_e[k * 512 + ff];
            p += pqS[fs][k] * Wsig[k];
        }
        CS[fs] = c; PS[fs] = p;
    }
    __syncthreads();

    float Ar[33];
    #pragma unroll
    for (int j = 0; j < 33; ++j) Ar[j] = AS[f_sub][j];
    float Cv = CS[f_sub], Pv = PS[f_sub];

    float vals[8];
    float s1 = 0.f, s2 = 0.f;
    #pragma unroll
    for (int t = 0; t < 8; ++t) {
        int l = l_loc + 32 * t;
        float v = 0.f;
        if (l < LMAX_) {
            const float* sp = &srcF[l * 33];
            float s = Cv;
            #pragma unroll
            for (int j = 0; j < 33; ++j) s += sp[j] * Ar[j];
            v = s * maskS[l];
            if (l >= 1) { s1 += v; s2 += v * v; }
        }
        vals[t] = v;
    }
    // reduce over the 32 l-lanes sharing f (xor<32 stays in half-wave)
    #pragma unroll
    for (int off = 16; off > 0; off >>= 1) {
        s1 += __shfl_xor(s1, off, 64);
        s2 += __shfl_xor(s2, off, 64);
    }
    float mu  = s1 * (1.f / 199.f);
    float var = s2 * (1.f / 199.f) - mu * mu;
    float inv = 1.0f / sqrtf(var + 1e-5f);

    _Float16* Sp = SB + ((size_t)(b * 512 + f)) * KPAD_;
    #pragma unroll
    for (int t = 0; t < 8; ++t) {
        int l = l_loc + 32 * t;
        float v = (l == 0) ? Pv : ((l < LMAX_) ? (vals[t] - mu) * inv : 0.f);
        Sp[l] = (_Float16)v;
    }
}

// ---------------------------------------------------------------------------
// K2: fused QK-GEMM + MLP, latency-oriented.
// Block = 64 kcell rows x full f=512, 4 waves, 2 blocks/CU (80 KB LDS).
// Phase 1 (no LDS, no barriers): acc[4][8]; A direct from atac (f32->f16,
//   guard k>=200), B direct from SB f16 (L2-hot). K-loop 7 iters (k<224;
//   [224,256) is all-zero on both sides). Wave owns f-cols wid*128.
// Qt (64x512 f16 swizzled) <- acc; barrier.
// Phase 2: wave owns 32 h-cols x all 64 rows; A from Qt, B=W1 direct global.
// Phase 3: wave owns 16 rows; A from Ht, B=W2 direct global. out f32.
// ---------------------------------------------------------------------------
__global__ __launch_bounds__(256, 2) void k_fused(
    const float* __restrict__ atac, const _Float16* __restrict__ SB,
    const float* __restrict__ W1, const float* __restrict__ b1,
    const float* __restrict__ W2, const float* __restrict__ b2,
    float* __restrict__ out)
{
    __shared__ _Float16 lds[40960];     // 80 KB: Qt 32768 | Ht 8192
    _Float16* Qt = lds;
    _Float16* Ht = lds + 32768;

    int tid = threadIdx.x, lane = tid & 63, wid = tid >> 6;
    int l15 = lane & 15, l4 = lane >> 4;
    int b = blockIdx.x >> 4;
    int row0 = (blockIdx.x & 15) * 64;

    const float*    Ab = atac + ((size_t)b * KC_ + row0) * LMAX_;
    const _Float16* Bb = SB + (size_t)b * FDIM_ * KPAD_;

    // ---------------- phase 1: QK GEMM (64 x 512, K=224), no LDS ----------
    floatx4 acc[4][8];
    #pragma unroll
    for (int m = 0; m < 4; ++m)
        #pragma unroll
        for (int n = 0; n < 8; ++n)
            acc[m][n] = (floatx4){0.f, 0.f, 0.f, 0.f};

    #pragma unroll
    for (int ks = 0; ks < 7; ++ks) {
        int kg = ks * 32 + l4 * 8;
        bool inr = kg < LMAX_;          // 200 % 8 == 0: whole group in/out
        f16x8 av[4], bv[8];
        #pragma unroll
        for (int m = 0; m < 4; ++m) {
            if (inr) {
                av[m] = ld8f(Ab + (size_t)(m * 16 + l15) * LMAX_ + kg);
            } else {
                #pragma unroll
                for (int j = 0; j < 8; ++j) av[m][j] = (_Float16)0.f;
            }
        }
        #pragma unroll
        for (int n = 0; n < 8; ++n)
            bv[n] = *(const f16x8*)(Bb + (size_t)(wid * 128 + n * 16 + l15) * KPAD_ + kg);
        #pragma unroll
        for (int m = 0; m < 4; ++m)
            #pragma unroll
            for (int n = 0; n < 8; ++n)
                acc[m][n] = __builtin_amdgcn_mfma_f32_16x16x32_f16(
                    av[m], bv[n], acc[m][n], 0, 0, 0);
    }

    // acc -> Qt (64 x 512 f16, swizzled on 8-f16 groups: g ^= row&7)
    #pragma unroll
    for (int m = 0; m < 4; ++m) {
        #pragma unroll
        for (int n = 0; n < 8; ++n) {
            int fcol = wid * 128 + n * 16 + l15;
            int g = fcol >> 3, w = fcol & 7;
            #pragma unroll
            for (int q = 0; q < 4; ++q) {
                int row = m * 16 + l4 * 4 + q;
                Qt[row * 512 + ((g ^ (row & 7)) << 3) + w] = (_Float16)acc[m][n][q];
            }
        }
    }
    __syncthreads();

    // ---------------- phase 2: MLP1, wave owns h-cols wid*32..+31 ----------
    floatx4 acc2[4][2];
    #pragma unroll
    for (int m = 0; m < 4; ++m)
        #pragma unroll
        for (int n = 0; n < 2; ++n)
            acc2[m][n] = (floatx4){0.f, 0.f, 0.f, 0.f};

    #pragma unroll
    for (int ks = 0; ks < 16; ++ks) {
        int g = ks * 4 + l4;
        f16x8 av[4], bv[2];
        #pragma unroll
        for (int m = 0; m < 4; ++m) {
            int row = m * 16 + l15;
            av[m] = *(const f16x8*)&Qt[row * 512 + ((g ^ (row & 7)) << 3)];
        }
        #pragma unroll
        for (int n = 0; n < 2; ++n)
            bv[n] = ld8f(W1 + (size_t)(wid * 32 + n * 16 + l15) * 512 + ks * 32 + l4 * 8);
        #pragma unroll
        for (int m = 0; m < 4; ++m)
            #pragma unroll
            for (int n = 0; n < 2; ++n)
                acc2[m][n] = __builtin_amdgcn_mfma_f32_16x16x32_f16(
                    av[m], bv[n], acc2[m][n], 0, 0, 0);
    }

    // relu(acc2 + b1) -> Ht (64 x 128, swizzled)
    #pragma unroll
    for (int n = 0; n < 2; ++n) {
        int col = wid * 32 + n * 16 + l15;
        float bb = b1[col];
        int cg = col >> 3, cw = col & 7;
        #pragma unroll
        for (int m = 0; m < 4; ++m) {
            #pragma unroll
            for (int q = 0; q < 4; ++q) {
                int row = m * 16 + l4 * 4 + q;
                float v = fmaxf(acc2[m][n][q] + bb, 0.f);
                Ht[row * 128 + ((cg ^ (row & 7)) << 3) + cw] = (_Float16)v;
            }
        }
    }
    __syncthreads();

    // ---------------- phase 3: MLP2, wave owns rows wid*16..+15 ------------
    floatx4 acc3[4];
    #pragma unroll
    for (int n = 0; n < 4; ++n) acc3[n] = (floatx4){0.f, 0.f, 0.f, 0.f};
    #pragma unroll
    for (int ks = 0; ks < 4; ++ks) {
        int g = ks * 4 + l4;
        int arow = wid * 16 + l15;
        f16x8 a = *(const f16x8*)&Ht[arow * 128 + ((g ^ (arow & 7)) << 3)];
        #pragma unroll
        for (int n = 0; n < 4; ++n) {
            f16x8 bw = ld8f(W2 + (size_t)(n * 16 + l15) * 128 + ks * 32 + l4 * 8);
            acc3[n] = __builtin_amdgcn_mfma_f32_16x16x32_f16(a, bw, acc3[n], 0, 0, 0);
        }
    }
    #pragma unroll
    for (int n = 0; n < 4; ++n) {
        float bb = b2[n * 16 + l15];
        #pragma unroll
        for (int q = 0; q < 4; ++q) {
            size_t grow = (size_t)b * KC_ + row0 + wid * 16 + l4 * 4 + q;
            out[grow * 64 + n * 16 + l15] = acc3[n][q] + bb;
        }
    }
}

// ---------------------------------------------------------------------------
extern "C" void kernel_launch(void* const* d_in, const int* in_sizes, int n_in,
                              void* d_out, int out_size, void* d_ws, size_t ws_size,
                              hipStream_t stream)
{
    const float* src  = (const float*)d_in[0];
    const float* prom = (const float*)d_in[1];
    const float* atac = (const float*)d_in[2];
    const float* mask = (const float*)d_in[3];
    const float* Wq_p = (const float*)d_in[4];
    const float* bq_p = (const float*)d_in[5];
    const float* Wq_e = (const float*)d_in[6];
    const float* bq_e = (const float*)d_in[7];
    const float* Wsig = (const float*)d_in[8];
    const float* bsig = (const float*)d_in[9];
    const float* W1   = (const float*)d_in[10];
    const float* b1   = (const float*)d_in[11];
    const float* W2   = (const float*)d_in[12];
    const float* b2   = (const float*)d_in[13];

    _Float16* SB = (_Float16*)d_ws;          // 16*512*256 = 2097152 f16
    float* outp = (float*)d_out;

    hipLaunchKernelGGL(k_qk, dim3(1024), dim3(256), 0, stream,
                       src, prom, mask, Wq_p, bq_p, Wq_e, bq_e, Wsig, bsig, SB);

    hipLaunchKernelGGL(k_fused, dim3(256), dim3(256), 0, stream,
                       atac, SB, W1, b1, W2, b2, outp);
}